// Round 1
// baseline (2145.220 us; speedup 1.0000x reference)
//
#include <hip/hip_runtime.h>
#include <math.h>

// Problem constants (match reference)
#define T_TOK 2048   // B*L
#define SEQ   1024   // L
#define DM    1024   // d_model
#define DI    2048   // d_inner
#define FFN   4096
#define NST   16     // d_state
#define DTR   64     // dt_rank
#define XD    96     // dt_rank + 2*d_state

// ---------------------------------------------------------------------------
// LayerNorm: one block per token, 256 threads x 4 elems = 1024 dims
// ---------------------------------------------------------------------------
__global__ __launch_bounds__(256) void ln_k(const float* __restrict__ in,
                                            const float* __restrict__ w,
                                            const float* __restrict__ bb,
                                            float* __restrict__ out) {
  int t = blockIdx.x;
  int tid = threadIdx.x;
  const float* row = in + (size_t)t * DM;
  float4 v = *(const float4*)(row + tid * 4);
  float s = v.x + v.y + v.z + v.w;
  __shared__ float sm[2][4];
  for (int off = 32; off > 0; off >>= 1) s += __shfl_down(s, off, 64);
  int wv = tid >> 6, ln = tid & 63;
  if (ln == 0) sm[0][wv] = s;
  __syncthreads();
  float mu = (sm[0][0] + sm[0][1] + sm[0][2] + sm[0][3]) * (1.0f / DM);
  float d0 = v.x - mu, d1 = v.y - mu, d2 = v.z - mu, d3 = v.w - mu;
  float sq = d0 * d0 + d1 * d1 + d2 * d2 + d3 * d3;
  for (int off = 32; off > 0; off >>= 1) sq += __shfl_down(sq, off, 64);
  if (ln == 0) sm[1][wv] = sq;
  __syncthreads();
  float var = (sm[1][0] + sm[1][1] + sm[1][2] + sm[1][3]) * (1.0f / DM);
  float rs = rsqrtf(var + 1e-5f);
  float4 w4 = *(const float4*)(w + tid * 4);
  float4 b4 = *(const float4*)(bb + tid * 4);
  float4 o;
  o.x = d0 * rs * w4.x + b4.x;
  o.y = d1 * rs * w4.y + b4.y;
  o.z = d2 * rs * w4.z + b4.z;
  o.w = d3 * rs * w4.w + b4.w;
  *(float4*)(out + (size_t)t * DM + tid * 4) = o;
}

// ---------------------------------------------------------------------------
// Generic fp32 NT GEMM: C[m,n] = sum_k A[m,k] * W[n,k]  (+ fused epilogue)
// epi: 0 none | 1 softplus(acc+bias) | 2 gelu_tanh(acc+bias) | 3 res+acc(+bias)
// ---------------------------------------------------------------------------
#define BM 64
#define BN 64
#define BK 32

__global__ __launch_bounds__(256) void gemm_nt(
    const float* __restrict__ A, int lda,
    const float* __restrict__ Bw, int ldb,
    float* __restrict__ C, int ldc,
    int M, int N, int K, int epi,
    const float* __restrict__ bias, const float* __restrict__ res) {
  __shared__ float As[BK][BM + 4];
  __shared__ float Bs[BK][BN + 4];
  int tid = threadIdx.x;
  int tx = tid & 15, ty = tid >> 4;
  int m0 = blockIdx.y * BM, n0 = blockIdx.x * BN;
  float acc[4][4] = {};
  for (int k0 = 0; k0 < K; k0 += BK) {
#pragma unroll
    for (int e = tid; e < (BM * BK) / 4; e += 256) {
      int r = e >> 3, c4 = e & 7;
      int gm = m0 + r;
      float4 v = make_float4(0.f, 0.f, 0.f, 0.f);
      if (gm < M) v = *(const float4*)(A + (size_t)gm * lda + k0 + c4 * 4);
      As[c4 * 4 + 0][r] = v.x;
      As[c4 * 4 + 1][r] = v.y;
      As[c4 * 4 + 2][r] = v.z;
      As[c4 * 4 + 3][r] = v.w;
    }
#pragma unroll
    for (int e = tid; e < (BN * BK) / 4; e += 256) {
      int r = e >> 3, c4 = e & 7;
      int gn = n0 + r;
      float4 v = make_float4(0.f, 0.f, 0.f, 0.f);
      if (gn < N) v = *(const float4*)(Bw + (size_t)gn * ldb + k0 + c4 * 4);
      Bs[c4 * 4 + 0][r] = v.x;
      Bs[c4 * 4 + 1][r] = v.y;
      Bs[c4 * 4 + 2][r] = v.z;
      Bs[c4 * 4 + 3][r] = v.w;
    }
    __syncthreads();
#pragma unroll
    for (int k = 0; k < BK; ++k) {
      float4 a4 = *(const float4*)&As[k][ty * 4];
      float4 b4 = *(const float4*)&Bs[k][tx * 4];
      float av[4] = {a4.x, a4.y, a4.z, a4.w};
      float bv[4] = {b4.x, b4.y, b4.z, b4.w};
#pragma unroll
      for (int i = 0; i < 4; i++)
#pragma unroll
        for (int j = 0; j < 4; j++) acc[i][j] = fmaf(av[i], bv[j], acc[i][j]);
    }
    __syncthreads();
  }
#pragma unroll
  for (int i = 0; i < 4; i++) {
    int gm = m0 + ty * 4 + i;
    if (gm >= M) continue;
#pragma unroll
    for (int j = 0; j < 4; j++) {
      int gn = n0 + tx * 4 + j;
      if (gn >= N) continue;
      float v = acc[i][j];
      if (epi == 1) {  // softplus(acc + bias)
        float x = v + bias[gn];
        v = (x > 20.f) ? x : log1pf(__expf(x));
      } else if (epi == 2) {  // tanh-approx gelu(acc + bias)  (jax default)
        float x = v + bias[gn];
        float u = 0.7978845608028654f * (x + 0.044715f * x * x * x);
        v = 0.5f * x * (1.f + tanhf(u));
      } else if (epi == 3) {  // residual + acc (+ bias)
        v += res[(size_t)gm * ldc + gn];
        if (bias) v += bias[gn];
      }
      C[(size_t)gm * ldc + gn] = v;
    }
  }
}

// ---------------------------------------------------------------------------
// Causal depthwise conv (k=4) + bias + SiLU.  Input: xz[:, :DI] (row len 2*DI)
// ---------------------------------------------------------------------------
__global__ __launch_bounds__(256) void conv_silu_k(const float* __restrict__ xz,
                                                   const float* __restrict__ cw,
                                                   const float* __restrict__ cb,
                                                   float* __restrict__ xc) {
  int idx = blockIdx.x * 256 + threadIdx.x;  // over T_TOK*DI
  int d = idx & (DI - 1);
  int t = idx >> 11;
  int l = t & (SEQ - 1);
  const float* base = xz + (size_t)t * (2 * DI) + d;
  float4 w4 = *(const float4*)(cw + d * 4);  // conv_w[d,0,0..3]
  float s = cb[d] + w4.w * base[0];
  if (l >= 1) s = fmaf(w4.z, base[-(2 * DI)], s);
  if (l >= 2) s = fmaf(w4.y, base[-2 * (2 * DI)], s);
  if (l >= 3) s = fmaf(w4.x, base[-3 * (2 * DI)], s);
  float y = s / (1.f + __expf(-s));  // silu
  xc[(size_t)t * DI + d] = y;
}

// ---------------------------------------------------------------------------
// Selective scan: one thread per (b, d, n) state; 16-lane butterfly reduce for
// y. Gating (silu(z)) and D-skip fused. y written in place over delta (dy).
// ---------------------------------------------------------------------------
__global__ __launch_bounds__(256) void scan_k(float* __restrict__ dy,
                                              const float* __restrict__ xc,
                                              const float* __restrict__ xz,
                                              const float* __restrict__ xdbl,
                                              const float* __restrict__ A_log,
                                              const float* __restrict__ Dsk) {
  int idx = blockIdx.x * 256 + threadIdx.x;  // over B*DI*NST = 65536
  int n = idx & 15;
  int d = (idx >> 4) & (DI - 1);
  int b = idx >> 15;
  float a = -__expf(A_log[d * NST + n]);
  float dskip = Dsk[d];
  float h = 0.f;
  int t = b * SEQ;
  for (int l = 0; l < SEQ; ++l, ++t) {
    float delta = dy[(size_t)t * DI + d];
    float xcv = xc[(size_t)t * DI + d];
    float Bv = xdbl[(size_t)t * XD + DTR + n];
    float Cv = xdbl[(size_t)t * XD + DTR + NST + n];
    float dA = __expf(delta * a);
    h = fmaf(dA, h, delta * xcv * Bv);
    float contrib = h * Cv;
    contrib += __shfl_xor(contrib, 1);
    contrib += __shfl_xor(contrib, 2);
    contrib += __shfl_xor(contrib, 4);
    contrib += __shfl_xor(contrib, 8);
    if (n == 0) {
      float zv = xz[(size_t)t * (2 * DI) + DI + d];
      float sig = zv / (1.f + __expf(-zv));
      dy[(size_t)t * DI + d] = (contrib + xcv * dskip) * sig;
    }
  }
}

// ---------------------------------------------------------------------------
extern "C" void kernel_launch(void* const* d_in, const int* in_sizes, int n_in,
                              void* d_out, int out_size, void* d_ws,
                              size_t ws_size, hipStream_t stream) {
  const float* x_in      = (const float*)d_in[0];
  const float* ln0_w     = (const float*)d_in[1];
  const float* ln0_b     = (const float*)d_in[2];
  const float* ln1_w     = (const float*)d_in[3];
  const float* ln1_b     = (const float*)d_in[4];
  const float* ln2_w     = (const float*)d_in[5];
  const float* ln2_b     = (const float*)d_in[6];
  const float* in_proj_w = (const float*)d_in[7];
  const float* conv_w    = (const float*)d_in[8];
  const float* conv_b    = (const float*)d_in[9];
  const float* x_proj_w  = (const float*)d_in[10];
  const float* dt_proj_w = (const float*)d_in[11];
  const float* dt_proj_b = (const float*)d_in[12];
  const float* A_log     = (const float*)d_in[13];
  const float* D_skip    = (const float*)d_in[14];
  const float* out_proj_w= (const float*)d_in[15];
  const float* ffn_w1    = (const float*)d_in[16];
  const float* ffn_b1    = (const float*)d_in[17];
  const float* ffn_w2    = (const float*)d_in[18];
  const float* ffn_b2    = (const float*)d_in[19];
  float* out = (float*)d_out;

  // Workspace layout (floats): total ~20.4M floats = ~82 MB
  float* ws    = (float*)d_ws;
  float* xws   = ws;                                 // [T,DM]   residual
  float* uws   = xws   + (size_t)T_TOK * DM;         // [T,DM]   LN out
  float* xzws  = uws   + (size_t)T_TOK * DM;         // [T,2*DI] xz / ffn hidden
  float* xcws  = xzws  + (size_t)T_TOK * 2 * DI;     // [T,DI]   conv+silu out
  float* xdbl  = xcws  + (size_t)T_TOK * DI;         // [T,96]
  float* dws   = xdbl  + (size_t)T_TOK * XD;         // [T,DI]   delta -> y

  // 1-2: LN0, LN1
  ln_k<<<T_TOK, 256, 0, stream>>>(x_in, ln0_w, ln0_b, xws);
  ln_k<<<T_TOK, 256, 0, stream>>>(xws, ln1_w, ln1_b, uws);
  // 3: in_proj  [T,DM] x [2DI,DM]^T -> [T,2DI]
  {
    dim3 g((2 * DI) / BN, T_TOK / BM);
    gemm_nt<<<g, 256, 0, stream>>>(uws, DM, in_proj_w, DM, xzws, 2 * DI,
                                   T_TOK, 2 * DI, DM, 0, nullptr, nullptr);
  }
  // 4: causal conv + silu
  conv_silu_k<<<(T_TOK * DI) / 256, 256, 0, stream>>>(xzws, conv_w, conv_b, xcws);
  // 5: x_proj  [T,DI] x [96,DI]^T -> [T,96]
  {
    dim3 g((XD + BN - 1) / BN, T_TOK / BM);
    gemm_nt<<<g, 256, 0, stream>>>(xcws, DI, x_proj_w, DI, xdbl, XD,
                                   T_TOK, XD, DI, 0, nullptr, nullptr);
  }
  // 6: dt_proj + softplus  [T,64](lda=96) x [DI,64]^T -> [T,DI]
  {
    dim3 g(DI / BN, T_TOK / BM);
    gemm_nt<<<g, 256, 0, stream>>>(xdbl, XD, dt_proj_w, DTR, dws, DI,
                                   T_TOK, DI, DTR, 1, dt_proj_b, nullptr);
  }
  // 7: selective scan + D-skip + gating (y in place over delta)
  scan_k<<<(2 * DI * NST) / 256, 256, 0, stream>>>(dws, xcws, xzws, xdbl,
                                                   A_log, D_skip);
  // 8: out_proj + residual  [T,DI] x [DM,DI]^T + xws -> xws
  {
    dim3 g(DM / BN, T_TOK / BM);
    gemm_nt<<<g, 256, 0, stream>>>(dws, DI, out_proj_w, DI, xws, DM,
                                   T_TOK, DM, DI, 3, nullptr, xws);
  }
  // 9: LN2
  ln_k<<<T_TOK, 256, 0, stream>>>(xws, ln2_w, ln2_b, uws);
  // 10: ffn1 + bias + gelu  [T,DM] x [FFN,DM]^T -> [T,FFN]
  {
    dim3 g(FFN / BN, T_TOK / BM);
    gemm_nt<<<g, 256, 0, stream>>>(uws, DM, ffn_w1, DM, xzws, FFN,
                                   T_TOK, FFN, DM, 2, ffn_b1, nullptr);
  }
  // 11: ffn2 + bias + residual -> d_out
  {
    dim3 g(DM / BN, T_TOK / BM);
    gemm_nt<<<g, 256, 0, stream>>>(xzws, FFN, ffn_w2, FFN, out, DM,
                                   T_TOK, DM, FFN, 3, ffn_b2, xws);
  }
}

// Round 2
// 871.280 us; speedup vs baseline: 2.4621x; 2.4621x over previous
//
#include <hip/hip_runtime.h>
#include <math.h>

// Problem constants (match reference)
#define T_TOK 2048   // B*L
#define SEQ   1024   // L
#define DM    1024   // d_model
#define DI    2048   // d_inner
#define FFN   4096
#define NST   16     // d_state
#define DTR   64     // dt_rank
#define XD    96     // dt_rank + 2*d_state
#define CHK   128    // scan chunk length
#define NCHK  8      // chunks per sequence

typedef __attribute__((ext_vector_type(8))) short short8;
typedef __attribute__((ext_vector_type(4))) float floatx4;

__device__ __forceinline__ unsigned short f2b(float f) {
  unsigned u = __float_as_uint(f);
  unsigned r = (u + 0x7fff + ((u >> 16) & 1)) >> 16;  // RNE
  return (unsigned short)r;
}
__device__ __forceinline__ float b2f(unsigned short s) {
  return __uint_as_float(((unsigned)s) << 16);
}

// ---------------------------------------------------------------------------
// fp32 -> bf16 bulk convert (n must be multiple of 1024); 4 elems/thread
// ---------------------------------------------------------------------------
__global__ __launch_bounds__(256) void f2b_k(const float* __restrict__ in,
                                             unsigned short* __restrict__ out) {
  int i = blockIdx.x * 256 + threadIdx.x;
  float4 v = ((const float4*)in)[i];
  ushort4 o;
  o.x = f2b(v.x); o.y = f2b(v.y); o.z = f2b(v.z); o.w = f2b(v.w);
  ((ushort4*)out)[i] = o;
}

// ---------------------------------------------------------------------------
// LayerNorm fp32 out: one block per token, 256 threads x 4 elems = 1024 dims
// ---------------------------------------------------------------------------
__global__ __launch_bounds__(256) void ln_k(const float* __restrict__ in,
                                            const float* __restrict__ w,
                                            const float* __restrict__ bb,
                                            float* __restrict__ out) {
  int t = blockIdx.x;
  int tid = threadIdx.x;
  const float* row = in + (size_t)t * DM;
  float4 v = *(const float4*)(row + tid * 4);
  float s = v.x + v.y + v.z + v.w;
  __shared__ float sm[2][4];
  for (int off = 32; off > 0; off >>= 1) s += __shfl_down(s, off, 64);
  int wv = tid >> 6, ln = tid & 63;
  if (ln == 0) sm[0][wv] = s;
  __syncthreads();
  float mu = (sm[0][0] + sm[0][1] + sm[0][2] + sm[0][3]) * (1.0f / DM);
  float d0 = v.x - mu, d1 = v.y - mu, d2 = v.z - mu, d3 = v.w - mu;
  float sq = d0 * d0 + d1 * d1 + d2 * d2 + d3 * d3;
  for (int off = 32; off > 0; off >>= 1) sq += __shfl_down(sq, off, 64);
  if (ln == 0) sm[1][wv] = sq;
  __syncthreads();
  float var = (sm[1][0] + sm[1][1] + sm[1][2] + sm[1][3]) * (1.0f / DM);
  float rs = rsqrtf(var + 1e-5f);
  float4 w4 = *(const float4*)(w + tid * 4);
  float4 b4 = *(const float4*)(bb + tid * 4);
  float4 o;
  o.x = d0 * rs * w4.x + b4.x;
  o.y = d1 * rs * w4.y + b4.y;
  o.z = d2 * rs * w4.z + b4.z;
  o.w = d3 * rs * w4.w + b4.w;
  *(float4*)(out + (size_t)t * DM + tid * 4) = o;
}

// LayerNorm bf16 out (same math, bf16 store)
__global__ __launch_bounds__(256) void ln_bf_k(const float* __restrict__ in,
                                               const float* __restrict__ w,
                                               const float* __restrict__ bb,
                                               unsigned short* __restrict__ out) {
  int t = blockIdx.x;
  int tid = threadIdx.x;
  const float* row = in + (size_t)t * DM;
  float4 v = *(const float4*)(row + tid * 4);
  float s = v.x + v.y + v.z + v.w;
  __shared__ float sm[2][4];
  for (int off = 32; off > 0; off >>= 1) s += __shfl_down(s, off, 64);
  int wv = tid >> 6, ln = tid & 63;
  if (ln == 0) sm[0][wv] = s;
  __syncthreads();
  float mu = (sm[0][0] + sm[0][1] + sm[0][2] + sm[0][3]) * (1.0f / DM);
  float d0 = v.x - mu, d1 = v.y - mu, d2 = v.z - mu, d3 = v.w - mu;
  float sq = d0 * d0 + d1 * d1 + d2 * d2 + d3 * d3;
  for (int off = 32; off > 0; off >>= 1) sq += __shfl_down(sq, off, 64);
  if (ln == 0) sm[1][wv] = sq;
  __syncthreads();
  float var = (sm[1][0] + sm[1][1] + sm[1][2] + sm[1][3]) * (1.0f / DM);
  float rs = rsqrtf(var + 1e-5f);
  float4 w4 = *(const float4*)(w + tid * 4);
  float4 b4 = *(const float4*)(bb + tid * 4);
  ushort4 o;
  o.x = f2b(d0 * rs * w4.x + b4.x);
  o.y = f2b(d1 * rs * w4.y + b4.y);
  o.z = f2b(d2 * rs * w4.z + b4.z);
  o.w = f2b(d3 * rs * w4.w + b4.w);
  *(ushort4*)(out + (size_t)t * DM + tid * 4) = o;
}

// ---------------------------------------------------------------------------
// bf16 MFMA GEMM (NT): C[m,n] = sum_k A[m,k]*W[n,k].  M,N multiples of 128,
// K multiple of 32.  128x128 tile, 4 waves (2x2), 16x16x32 MFMA.
// epi: 0 fp32 store | 1 bf16 store | 2 gelu(acc+bias) bf16 store
//      3 acc+res fp32 | 4 acc+bias+res fp32
// ---------------------------------------------------------------------------
__global__ __launch_bounds__(256) void gemm_bf16(
    const unsigned short* __restrict__ A, int lda,
    const unsigned short* __restrict__ Bw, int ldb,
    void* __restrict__ Cout, int ldc, int K, int epi,
    const float* __restrict__ bias, const float* __restrict__ res) {
  __shared__ unsigned short As[4][128][8];  // [k-slab][row][8k]
  __shared__ unsigned short Bs[4][128][8];
  int tid = threadIdx.x;
  int lane = tid & 63, wv = tid >> 6;
  int wr = wv >> 1, wc = wv & 1;
  int m0 = blockIdx.y * 128, n0 = blockIdx.x * 128;
  int ml = lane & 15, kq = lane >> 4;
  floatx4 acc[4][4] = {};
  for (int k0 = 0; k0 < K; k0 += 32) {
#pragma unroll
    for (int i = 0; i < 2; ++i) {
      int c = tid + i * 256;
      int row = c & 127, slab = c >> 7;
      *(int4*)&As[slab][row][0] =
          *(const int4*)(A + (size_t)(m0 + row) * lda + k0 + slab * 8);
      *(int4*)&Bs[slab][row][0] =
          *(const int4*)(Bw + (size_t)(n0 + row) * ldb + k0 + slab * 8);
    }
    __syncthreads();
    short8 af[4], bfr[4];
#pragma unroll
    for (int i = 0; i < 4; ++i)
      af[i] = *(const short8*)&As[kq][wr * 64 + i * 16 + ml][0];
#pragma unroll
    for (int j = 0; j < 4; ++j)
      bfr[j] = *(const short8*)&Bs[kq][wc * 64 + j * 16 + ml][0];
#pragma unroll
    for (int i = 0; i < 4; ++i)
#pragma unroll
      for (int j = 0; j < 4; ++j)
        acc[i][j] =
            __builtin_amdgcn_mfma_f32_16x16x32_bf16(af[i], bfr[j], acc[i][j], 0, 0, 0);
    __syncthreads();
  }
  // epilogue: D row = (lane>>4)*4 + r, col = lane&15
#pragma unroll
  for (int i = 0; i < 4; ++i) {
    int gm = m0 + wr * 64 + i * 16 + kq * 4;
#pragma unroll
    for (int j = 0; j < 4; ++j) {
      int gn = n0 + wc * 64 + j * 16 + ml;
#pragma unroll
      for (int r = 0; r < 4; ++r) {
        float v = acc[i][j][r];
        size_t off = (size_t)(gm + r) * ldc + gn;
        if (epi == 0) {
          ((float*)Cout)[off] = v;
        } else if (epi == 1) {
          ((unsigned short*)Cout)[off] = f2b(v);
        } else if (epi == 2) {
          float x = v + bias[gn];
          float u = 0.7978845608028654f * (x + 0.044715f * x * x * x);
          ((unsigned short*)Cout)[off] = f2b(0.5f * x * (1.f + tanhf(u)));
        } else if (epi == 3) {
          ((float*)Cout)[off] = v + res[off];
        } else {
          ((float*)Cout)[off] = v + bias[gn] + res[off];
        }
      }
    }
  }
}

// ---------------------------------------------------------------------------
// Generic fp32 NT GEMM (small ops: x_proj, dt_proj).  epi: 0 none | 1 softplus
// ---------------------------------------------------------------------------
#define BM 64
#define BN 64
#define BK 32

__global__ __launch_bounds__(256) void gemm_nt(
    const float* __restrict__ A, int lda,
    const float* __restrict__ Bw, int ldb,
    float* __restrict__ C, int ldc,
    int M, int N, int K, int epi, const float* __restrict__ bias) {
  __shared__ float As[BK][BM + 4];
  __shared__ float Bs[BK][BN + 4];
  int tid = threadIdx.x;
  int tx = tid & 15, ty = tid >> 4;
  int m0 = blockIdx.y * BM, n0 = blockIdx.x * BN;
  float acc[4][4] = {};
  for (int k0 = 0; k0 < K; k0 += BK) {
#pragma unroll
    for (int e = tid; e < (BM * BK) / 4; e += 256) {
      int r = e >> 3, c4 = e & 7;
      int gm = m0 + r;
      float4 v = make_float4(0.f, 0.f, 0.f, 0.f);
      if (gm < M) v = *(const float4*)(A + (size_t)gm * lda + k0 + c4 * 4);
      As[c4 * 4 + 0][r] = v.x;
      As[c4 * 4 + 1][r] = v.y;
      As[c4 * 4 + 2][r] = v.z;
      As[c4 * 4 + 3][r] = v.w;
    }
#pragma unroll
    for (int e = tid; e < (BN * BK) / 4; e += 256) {
      int r = e >> 3, c4 = e & 7;
      int gn = n0 + r;
      float4 v = make_float4(0.f, 0.f, 0.f, 0.f);
      if (gn < N) v = *(const float4*)(Bw + (size_t)gn * ldb + k0 + c4 * 4);
      Bs[c4 * 4 + 0][r] = v.x;
      Bs[c4 * 4 + 1][r] = v.y;
      Bs[c4 * 4 + 2][r] = v.z;
      Bs[c4 * 4 + 3][r] = v.w;
    }
    __syncthreads();
#pragma unroll
    for (int k = 0; k < BK; ++k) {
      float4 a4 = *(const float4*)&As[k][ty * 4];
      float4 b4 = *(const float4*)&Bs[k][tx * 4];
      float av[4] = {a4.x, a4.y, a4.z, a4.w};
      float bv[4] = {b4.x, b4.y, b4.z, b4.w};
#pragma unroll
      for (int i = 0; i < 4; i++)
#pragma unroll
        for (int j = 0; j < 4; j++) acc[i][j] = fmaf(av[i], bv[j], acc[i][j]);
    }
    __syncthreads();
  }
#pragma unroll
  for (int i = 0; i < 4; i++) {
    int gm = m0 + ty * 4 + i;
    if (gm >= M) continue;
#pragma unroll
    for (int j = 0; j < 4; j++) {
      int gn = n0 + tx * 4 + j;
      if (gn >= N) continue;
      float v = acc[i][j];
      if (epi == 1) {
        float x = v + bias[gn];
        v = (x > 20.f) ? x : log1pf(__expf(x));
      }
      C[(size_t)gm * ldc + gn] = v;
    }
  }
}

// ---------------------------------------------------------------------------
// Causal depthwise conv (k=4) + bias + SiLU.  Input xh [T,DI] fp32.
// ---------------------------------------------------------------------------
__global__ __launch_bounds__(256) void conv_silu_k(const float* __restrict__ xh,
                                                   const float* __restrict__ cw,
                                                   const float* __restrict__ cb,
                                                   float* __restrict__ xc) {
  int idx = blockIdx.x * 256 + threadIdx.x;  // over T_TOK*DI
  int d = idx & (DI - 1);
  int t = idx >> 11;
  int l = t & (SEQ - 1);
  const float* base = xh + (size_t)t * DI + d;
  float4 w4 = *(const float4*)(cw + d * 4);  // conv_w[d,0,0..3]
  float s = cb[d] + w4.w * base[0];
  if (l >= 1) s = fmaf(w4.z, base[-DI], s);
  if (l >= 2) s = fmaf(w4.y, base[-2 * DI], s);
  if (l >= 3) s = fmaf(w4.x, base[-3 * DI], s);
  float y = s / (1.f + __expf(-s));  // silu
  xc[(size_t)t * DI + d] = y;
}

// ---------------------------------------------------------------------------
// Chunked selective scan, pass 1: per-chunk (prod dA, local h_end).
// idx bits: [3:0]=n  [14:4]=d  [17:15]=chunk  [18]=b
// ---------------------------------------------------------------------------
__global__ __launch_bounds__(256) void scan1_k(
    const float* __restrict__ delta, const float* __restrict__ xc,
    const float* __restrict__ xdbl, const float* __restrict__ A_log,
    float* __restrict__ hend, float* __restrict__ aprod) {
  int idx = blockIdx.x * 256 + threadIdx.x;
  int n = idx & 15;
  int d = (idx >> 4) & (DI - 1);
  int c = (idx >> 15) & (NCHK - 1);
  int b = idx >> 18;
  float a = -__expf(A_log[d * NST + n]);
  float h = 0.f, ap = 1.f;
  int t = b * SEQ + c * CHK;
#pragma unroll 4
  for (int l = 0; l < CHK; ++l, ++t) {
    float dv = delta[(size_t)t * DI + d];
    float xv = xc[(size_t)t * DI + d];
    float Bv = xdbl[(size_t)t * XD + DTR + n];
    float dA = __expf(dv * a);
    ap *= dA;
    h = fmaf(dA, h, dv * xv * Bv);
  }
  hend[idx] = h;
  aprod[idx] = ap;
}

// ---------------------------------------------------------------------------
// Chunked selective scan, pass 2: compose prior chunk summaries, replay chunk,
// 16-lane butterfly reduce, fuse D-skip + silu(z) gate, write y as bf16.
// ---------------------------------------------------------------------------
__global__ __launch_bounds__(256) void scan2_k(
    const float* __restrict__ delta, const float* __restrict__ xc,
    const float* __restrict__ xdbl, const unsigned short* __restrict__ zbf,
    const float* __restrict__ A_log, const float* __restrict__ Dsk,
    const float* __restrict__ hend, const float* __restrict__ aprod,
    unsigned short* __restrict__ y) {
  int idx = blockIdx.x * 256 + threadIdx.x;
  int n = idx & 15;
  int d = (idx >> 4) & (DI - 1);
  int c = (idx >> 15) & (NCHK - 1);
  int b = idx >> 18;
  float a = -__expf(A_log[d * NST + n]);
  float dskip = Dsk[d];
  // compose h_init from prior chunk summaries
  float h = 0.f;
  int base = idx & ~((NCHK - 1) << 15);
  for (int pc = 0; pc < c; ++pc) {
    int pi = base | (pc << 15);
    h = fmaf(aprod[pi], h, hend[pi]);
  }
  int t = b * SEQ + c * CHK;
#pragma unroll 2
  for (int l = 0; l < CHK; ++l, ++t) {
    float dv = delta[(size_t)t * DI + d];
    float xv = xc[(size_t)t * DI + d];
    float Bv = xdbl[(size_t)t * XD + DTR + n];
    float Cv = xdbl[(size_t)t * XD + DTR + NST + n];
    float dA = __expf(dv * a);
    h = fmaf(dA, h, dv * xv * Bv);
    float contrib = h * Cv;
    contrib += __shfl_xor(contrib, 1);
    contrib += __shfl_xor(contrib, 2);
    contrib += __shfl_xor(contrib, 4);
    contrib += __shfl_xor(contrib, 8);
    if (n == 0) {
      float zv = b2f(zbf[(size_t)t * DI + d]);
      float sig = zv / (1.f + __expf(-zv));
      y[(size_t)t * DI + d] = f2b((contrib + xv * dskip) * sig);
    }
  }
}

// ---------------------------------------------------------------------------
extern "C" void kernel_launch(void* const* d_in, const int* in_sizes, int n_in,
                              void* d_out, int out_size, void* d_ws,
                              size_t ws_size, hipStream_t stream) {
  const float* x_in      = (const float*)d_in[0];
  const float* ln0_w     = (const float*)d_in[1];
  const float* ln0_b     = (const float*)d_in[2];
  const float* ln1_w     = (const float*)d_in[3];
  const float* ln1_b     = (const float*)d_in[4];
  const float* ln2_w     = (const float*)d_in[5];
  const float* ln2_b     = (const float*)d_in[6];
  const float* in_proj_w = (const float*)d_in[7];
  const float* conv_w    = (const float*)d_in[8];
  const float* conv_b    = (const float*)d_in[9];
  const float* x_proj_w  = (const float*)d_in[10];
  const float* dt_proj_w = (const float*)d_in[11];
  const float* dt_proj_b = (const float*)d_in[12];
  const float* A_log     = (const float*)d_in[13];
  const float* D_skip    = (const float*)d_in[14];
  const float* out_proj_w= (const float*)d_in[15];
  const float* ffn_w1    = (const float*)d_in[16];
  const float* ffn_b1    = (const float*)d_in[17];
  const float* ffn_w2    = (const float*)d_in[18];
  const float* ffn_b2    = (const float*)d_in[19];
  float* out = (float*)d_out;

  // Workspace layout (floats), liveness-aliased, total 20.12M floats = 80.5 MB
  float* ws    = (float*)d_ws;
  float* xws   = ws;                     // [T,DM] fp32 residual          2.10M
  float* big   = xws + 2097152;          // region: xh / ybf / hbf        4.19M
  float* zbf_f = big + 4194304;          // [T,DI] bf16 z-gate            2.10M
  float* xcws  = zbf_f + 2097152;        // [T,DI] fp32 conv+silu out     4.19M
  float* xdbl  = xcws + 4194304;         // [T,96] fp32                   0.20M
  float* dws   = xdbl + 196608;          // [T,DI] fp32 delta             4.19M
  float* ubf_f = dws + 4194304;          // [T,DM] bf16 LN out            1.05M
  float* wbf_f = ubf_f + 1048576;        // bf16 weight staging           2.10M
  // aliases
  float*          xh   = big;                       // [T,DI] fp32 (dies after conv)
  unsigned short* ybf  = (unsigned short*)big;      // [T,DI] bf16 (scan2->out_proj)
  unsigned short* hbf  = (unsigned short*)big;      // [T,FFN] bf16 (ffn1->ffn2)
  unsigned short* zbf  = (unsigned short*)zbf_f;
  unsigned short* ubf  = (unsigned short*)ubf_f;
  unsigned short* wbf  = (unsigned short*)wbf_f;
  float* hend  = wbf_f;                  // [524288] (wbf dead during scan)
  float* aprod = wbf_f + 524288;         // [524288]

  // 1: convert in_proj_w -> bf16 (4096x1024)
  f2b_k<<<(4096 * 1024) / 1024, 256, 0, stream>>>(in_proj_w, wbf);
  // 2-3: LN0 (fp32), LN1 (bf16)
  ln_k<<<T_TOK, 256, 0, stream>>>(x_in, ln0_w, ln0_b, xws);
  ln_bf_k<<<T_TOK, 256, 0, stream>>>(xws, ln1_w, ln1_b, ubf);
  // 4: in_proj x-half -> xh fp32 ; 5: z-half -> zbf bf16
  {
    dim3 g(DI / 128, T_TOK / 128);
    gemm_bf16<<<g, 256, 0, stream>>>(ubf, DM, wbf, DM, xh, DI, DM, 0, nullptr, nullptr);
    gemm_bf16<<<g, 256, 0, stream>>>(ubf, DM, wbf + (size_t)DI * DM, DM, zbf, DI, DM, 1,
                                     nullptr, nullptr);
  }
  // 6: causal conv + silu
  conv_silu_k<<<(T_TOK * DI) / 256, 256, 0, stream>>>(xh, conv_w, conv_b, xcws);
  // 7: x_proj (fp32)  [T,DI] x [96,DI]^T -> [T,96]
  {
    dim3 g((XD + BN - 1) / BN, T_TOK / BM);
    gemm_nt<<<g, 256, 0, stream>>>(xcws, DI, x_proj_w, DI, xdbl, XD,
                                   T_TOK, XD, DI, 0, nullptr);
  }
  // 8: dt_proj + softplus (fp32)  [T,64](lda=96) x [DI,64]^T -> delta
  {
    dim3 g(DI / BN, T_TOK / BM);
    gemm_nt<<<g, 256, 0, stream>>>(xdbl, XD, dt_proj_w, DTR, dws, DI,
                                   T_TOK, DI, DTR, 1, dt_proj_b);
  }
  // 9-10: chunked scan (hend/aprod live in wbf region — weights dead here)
  scan1_k<<<(2 * DI * NST * NCHK) / 256, 256, 0, stream>>>(dws, xcws, xdbl, A_log,
                                                           hend, aprod);
  scan2_k<<<(2 * DI * NST * NCHK) / 256, 256, 0, stream>>>(dws, xcws, xdbl, zbf,
                                                           A_log, D_skip, hend, aprod,
                                                           ybf);
  // 11-12: out_proj (bf16) + residual -> xws
  f2b_k<<<(DM * DI) / 1024, 256, 0, stream>>>(out_proj_w, wbf);
  {
    dim3 g(DM / 128, T_TOK / 128);
    gemm_bf16<<<g, 256, 0, stream>>>(ybf, DI, wbf, DI, xws, DM, DI, 3, nullptr, xws);
  }
  // 13: LN2 -> bf16
  ln_bf_k<<<T_TOK, 256, 0, stream>>>(xws, ln2_w, ln2_b, ubf);
  // 14-15: ffn1 + bias + gelu -> hbf bf16
  f2b_k<<<(FFN * DM) / 1024, 256, 0, stream>>>(ffn_w1, wbf);
  {
    dim3 g(FFN / 128, T_TOK / 128);
    gemm_bf16<<<g, 256, 0, stream>>>(ubf, DM, wbf, DM, hbf, FFN, DM, 2, ffn_b1, nullptr);
  }
  // 16-17: ffn2 + bias + residual -> d_out fp32
  f2b_k<<<(DM * FFN) / 1024, 256, 0, stream>>>(ffn_w2, wbf);
  {
    dim3 g(DM / 128, T_TOK / 128);
    gemm_bf16<<<g, 256, 0, stream>>>(hbf, FFN, wbf, FFN, out, DM, FFN, 4, ffn_b2, xws);
  }
}

// Round 3
// 791.871 us; speedup vs baseline: 2.7091x; 1.1003x over previous
//
#include <hip/hip_runtime.h>
#include <math.h>

// Problem constants (match reference)
#define T_TOK 2048   // B*L
#define SEQ   1024   // L
#define DM    1024   // d_model
#define DI    2048   // d_inner
#define FFN   4096
#define NST   16     // d_state
#define DTR   64     // dt_rank
#define XD    96     // dt_rank + 2*d_state
#define CHK   128    // scan chunk length
#define NCHK  8      // chunks per sequence
#define SPLITK 8     // x_proj K-splits (K chunk = 256)

typedef __attribute__((ext_vector_type(8))) short short8;
typedef __attribute__((ext_vector_type(4))) float floatx4;

__device__ __forceinline__ unsigned short f2b(float f) {
  unsigned u = __float_as_uint(f);
  unsigned r = (u + 0x7fff + ((u >> 16) & 1)) >> 16;  // RNE
  return (unsigned short)r;
}
__device__ __forceinline__ float b2f(unsigned short s) {
  return __uint_as_float(((unsigned)s) << 16);
}

// async global->LDS, 16 B per lane. lds must be the wave-uniform base
// (lane 0's destination); HW adds lane*16. g is the per-lane global addr.
typedef const __attribute__((address_space(1))) unsigned int g_uint;
typedef __attribute__((address_space(3))) unsigned int l_uint;
__device__ __forceinline__ void async16(void* lds, const void* g) {
  __builtin_amdgcn_global_load_lds((g_uint*)(size_t)g,
                                   (l_uint*)(unsigned)(size_t)lds, 16, 0, 0);
}

// ---------------------------------------------------------------------------
// fp32 -> bf16 bulk convert (n must be multiple of 1024); 4 elems/thread
// ---------------------------------------------------------------------------
__global__ __launch_bounds__(256) void f2b_k(const float* __restrict__ in,
                                             unsigned short* __restrict__ out) {
  int i = blockIdx.x * 256 + threadIdx.x;
  float4 v = ((const float4*)in)[i];
  ushort4 o;
  o.x = f2b(v.x); o.y = f2b(v.y); o.z = f2b(v.z); o.w = f2b(v.w);
  ((ushort4*)out)[i] = o;
}

// ---------------------------------------------------------------------------
// LayerNorm fp32 out: one block per token, 256 threads x 4 elems = 1024 dims
// ---------------------------------------------------------------------------
__global__ __launch_bounds__(256) void ln_k(const float* __restrict__ in,
                                            const float* __restrict__ w,
                                            const float* __restrict__ bb,
                                            float* __restrict__ out) {
  int t = blockIdx.x;
  int tid = threadIdx.x;
  const float* row = in + (size_t)t * DM;
  float4 v = *(const float4*)(row + tid * 4);
  float s = v.x + v.y + v.z + v.w;
  __shared__ float sm[2][4];
  for (int off = 32; off > 0; off >>= 1) s += __shfl_down(s, off, 64);
  int wv = tid >> 6, ln = tid & 63;
  if (ln == 0) sm[0][wv] = s;
  __syncthreads();
  float mu = (sm[0][0] + sm[0][1] + sm[0][2] + sm[0][3]) * (1.0f / DM);
  float d0 = v.x - mu, d1 = v.y - mu, d2 = v.z - mu, d3 = v.w - mu;
  float sq = d0 * d0 + d1 * d1 + d2 * d2 + d3 * d3;
  for (int off = 32; off > 0; off >>= 1) sq += __shfl_down(sq, off, 64);
  if (ln == 0) sm[1][wv] = sq;
  __syncthreads();
  float var = (sm[1][0] + sm[1][1] + sm[1][2] + sm[1][3]) * (1.0f / DM);
  float rs = rsqrtf(var + 1e-5f);
  float4 w4 = *(const float4*)(w + tid * 4);
  float4 b4 = *(const float4*)(bb + tid * 4);
  float4 o;
  o.x = d0 * rs * w4.x + b4.x;
  o.y = d1 * rs * w4.y + b4.y;
  o.z = d2 * rs * w4.z + b4.z;
  o.w = d3 * rs * w4.w + b4.w;
  *(float4*)(out + (size_t)t * DM + tid * 4) = o;
}

// LayerNorm bf16 out
__global__ __launch_bounds__(256) void ln_bf_k(const float* __restrict__ in,
                                               const float* __restrict__ w,
                                               const float* __restrict__ bb,
                                               unsigned short* __restrict__ out) {
  int t = blockIdx.x;
  int tid = threadIdx.x;
  const float* row = in + (size_t)t * DM;
  float4 v = *(const float4*)(row + tid * 4);
  float s = v.x + v.y + v.z + v.w;
  __shared__ float sm[2][4];
  for (int off = 32; off > 0; off >>= 1) s += __shfl_down(s, off, 64);
  int wv = tid >> 6, ln = tid & 63;
  if (ln == 0) sm[0][wv] = s;
  __syncthreads();
  float mu = (sm[0][0] + sm[0][1] + sm[0][2] + sm[0][3]) * (1.0f / DM);
  float d0 = v.x - mu, d1 = v.y - mu, d2 = v.z - mu, d3 = v.w - mu;
  float sq = d0 * d0 + d1 * d1 + d2 * d2 + d3 * d3;
  for (int off = 32; off > 0; off >>= 1) sq += __shfl_down(sq, off, 64);
  if (ln == 0) sm[1][wv] = sq;
  __syncthreads();
  float var = (sm[1][0] + sm[1][1] + sm[1][2] + sm[1][3]) * (1.0f / DM);
  float rs = rsqrtf(var + 1e-5f);
  float4 w4 = *(const float4*)(w + tid * 4);
  float4 b4 = *(const float4*)(bb + tid * 4);
  ushort4 o;
  o.x = f2b(d0 * rs * w4.x + b4.x);
  o.y = f2b(d1 * rs * w4.y + b4.y);
  o.z = f2b(d2 * rs * w4.z + b4.z);
  o.w = f2b(d3 * rs * w4.w + b4.w);
  *(ushort4*)(out + (size_t)t * DM + tid * 4) = o;
}

// ---------------------------------------------------------------------------
// bf16 MFMA GEMM (NT): C[m,n] = sum_k A[m,k]*W[n,k].  M,N multiples of 128,
// K multiple of 32.  128x128 tile, 4 waves (2x2), 16x16x32 MFMA,
// global_load_lds (width 16) staging.
// epi: 0 fp32 | 1 bf16 | 2 gelu(acc+bias) bf16 | 3 acc+res fp32
//      4 acc+bias+res fp32 | 5 softplus(acc+bias) fp32
// ---------------------------------------------------------------------------
__global__ __launch_bounds__(256) void gemm_bf16(
    const unsigned short* __restrict__ A, int lda,
    const unsigned short* __restrict__ Bw, int ldb,
    void* __restrict__ Cout, int ldc, int K, int epi,
    const float* __restrict__ bias, const float* __restrict__ res) {
  __shared__ __align__(16) unsigned short As[4][128][8];  // [k-slab][row][8k]
  __shared__ __align__(16) unsigned short Bs[4][128][8];
  int tid = threadIdx.x;
  int lane = tid & 63, wv = tid >> 6;
  int wr = wv >> 1, wc = wv & 1;
  int m0 = blockIdx.y * 128, n0 = blockIdx.x * 128;
  int ml = lane & 15, kq = lane >> 4;
  floatx4 acc[4][4] = {};
  for (int k0 = 0; k0 < K; k0 += 32) {
#pragma unroll
    for (int i = 0; i < 2; ++i) {
      int c = tid + i * 256;
      int row = c & 127, slab = c >> 7;          // per-lane
      int cw = wv * 64 + i * 256;
      int row0 = cw & 127, slab0 = cw >> 7;      // wave-uniform
      async16(&As[slab0][row0][0], A + (size_t)(m0 + row) * lda + k0 + slab * 8);
      async16(&Bs[slab0][row0][0], Bw + (size_t)(n0 + row) * ldb + k0 + slab * 8);
    }
    __syncthreads();
    short8 af[4], bfr[4];
#pragma unroll
    for (int i = 0; i < 4; ++i)
      af[i] = *(const short8*)&As[kq][wr * 64 + i * 16 + ml][0];
#pragma unroll
    for (int j = 0; j < 4; ++j)
      bfr[j] = *(const short8*)&Bs[kq][wc * 64 + j * 16 + ml][0];
#pragma unroll
    for (int i = 0; i < 4; ++i)
#pragma unroll
      for (int j = 0; j < 4; ++j)
        acc[i][j] =
            __builtin_amdgcn_mfma_f32_16x16x32_bf16(af[i], bfr[j], acc[i][j], 0, 0, 0);
    __syncthreads();
  }
  // epilogue: D row = (lane>>4)*4 + r, col = lane&15
#pragma unroll
  for (int i = 0; i < 4; ++i) {
    int gm = m0 + wr * 64 + i * 16 + kq * 4;
#pragma unroll
    for (int j = 0; j < 4; ++j) {
      int gn = n0 + wc * 64 + j * 16 + ml;
#pragma unroll
      for (int r = 0; r < 4; ++r) {
        float v = acc[i][j][r];
        size_t off = (size_t)(gm + r) * ldc + gn;
        if (epi == 0) {
          ((float*)Cout)[off] = v;
        } else if (epi == 1) {
          ((unsigned short*)Cout)[off] = f2b(v);
        } else if (epi == 2) {
          float x = v + bias[gn];
          float u = 0.7978845608028654f * (x + 0.044715f * x * x * x);
          ((unsigned short*)Cout)[off] = f2b(0.5f * x * (1.f + tanhf(u)));
        } else if (epi == 3) {
          ((float*)Cout)[off] = v + res[off];
        } else if (epi == 4) {
          ((float*)Cout)[off] = v + bias[gn] + res[off];
        } else {  // 5: softplus(acc + bias)
          float x = v + bias[gn];
          ((float*)Cout)[off] = (x > 20.f) ? x : log1pf(__expf(x));
        }
      }
    }
  }
}

// ---------------------------------------------------------------------------
// x_proj split-K bf16 MFMA: part[ks][m][n] = sum_{k in chunk ks} xcb[m,k]*W[n,k]
// M-tile 64 (4 waves x 16 rows), N=96 (6 frags), K-chunk 256. B staged once.
// ---------------------------------------------------------------------------
__global__ __launch_bounds__(256) void xproj_k(
    const unsigned short* __restrict__ xcb, const unsigned short* __restrict__ wpb,
    float* __restrict__ part) {
  __shared__ __align__(16) unsigned short As[4][64][8];   // [slab][row][8]
  __shared__ __align__(16) unsigned short Bs[32][96][8];  // [slab][row][8]
  int tid = threadIdx.x;
  int lane = tid & 63, wv = tid >> 6;
  int ml = lane & 15, kq = lane >> 4;
  int m0 = blockIdx.x * 64;
  int ks = blockIdx.y;
  int kbase = ks * 256;
  // stage full B chunk (96 x 256) once, coalesced over k
  for (int e = tid; e < 3072; e += 256) {
    int row = e >> 5, slab = e & 31;
    *(int4*)&Bs[slab][row][0] = *(const int4*)(wpb + (size_t)row * DI + kbase + slab * 8);
  }
  floatx4 acc[6] = {};
  for (int s = 0; s < 8; ++s) {
    // stage A 64x32: one async16 per thread; wave wv = slab, lane = row
    async16(&As[wv][0][0],
            xcb + (size_t)(m0 + lane) * DI + kbase + s * 32 + wv * 8);
    __syncthreads();
    short8 af = *(const short8*)&As[kq][wv * 16 + ml][0];
#pragma unroll
    for (int j = 0; j < 6; ++j) {
      short8 bf = *(const short8*)&Bs[s * 4 + kq][j * 16 + ml][0];
      acc[j] = __builtin_amdgcn_mfma_f32_16x16x32_bf16(af, bf, acc[j], 0, 0, 0);
    }
    __syncthreads();
  }
  float* dst = part + (size_t)ks * (T_TOK * XD);
#pragma unroll
  for (int j = 0; j < 6; ++j) {
    int gn = j * 16 + ml;
    int gm = m0 + wv * 16 + kq * 4;
#pragma unroll
    for (int r = 0; r < 4; ++r) dst[(size_t)(gm + r) * XD + gn] = acc[j][r];
  }
}

// reduce split-K partials -> x_dbl fp32 [T,96]; also dt part as bf16 [T,64]
__global__ __launch_bounds__(256) void xreduce_k(const float* __restrict__ part,
                                                 float* __restrict__ xdbl,
                                                 unsigned short* __restrict__ dtb) {
  int i = blockIdx.x * 256 + threadIdx.x;  // < T_TOK*XD
  float s = 0.f;
#pragma unroll
  for (int ks = 0; ks < SPLITK; ++ks) s += part[(size_t)ks * (T_TOK * XD) + i];
  xdbl[i] = s;
  int t = i / XD, c = i - t * XD;
  if (c < DTR) dtb[(size_t)t * DTR + c] = f2b(s);
}

// ---------------------------------------------------------------------------
// Causal depthwise conv (k=4) + bias + SiLU. Emits fp32 (scan) + bf16 (x_proj).
// ---------------------------------------------------------------------------
__global__ __launch_bounds__(256) void conv_silu_k(const float* __restrict__ xh,
                                                   const float* __restrict__ cw,
                                                   const float* __restrict__ cb,
                                                   float* __restrict__ xc,
                                                   unsigned short* __restrict__ xcb) {
  int idx = blockIdx.x * 256 + threadIdx.x;  // over T_TOK*DI
  int d = idx & (DI - 1);
  int t = idx >> 11;
  int l = t & (SEQ - 1);
  const float* base = xh + (size_t)t * DI + d;
  float4 w4 = *(const float4*)(cw + d * 4);
  float s = cb[d] + w4.w * base[0];
  if (l >= 1) s = fmaf(w4.z, base[-DI], s);
  if (l >= 2) s = fmaf(w4.y, base[-2 * DI], s);
  if (l >= 3) s = fmaf(w4.x, base[-3 * DI], s);
  float y = s / (1.f + __expf(-s));  // silu
  xc[(size_t)t * DI + d] = y;
  xcb[(size_t)t * DI + d] = f2b(y);
}

// ---------------------------------------------------------------------------
// Chunked selective scan, pass 1: per-chunk (prod dA, local h_end).
// ---------------------------------------------------------------------------
__global__ __launch_bounds__(256) void scan1_k(
    const float* __restrict__ delta, const float* __restrict__ xc,
    const float* __restrict__ xdbl, const float* __restrict__ A_log,
    float* __restrict__ hend, float* __restrict__ aprod) {
  int idx = blockIdx.x * 256 + threadIdx.x;
  int n = idx & 15;
  int d = (idx >> 4) & (DI - 1);
  int c = (idx >> 15) & (NCHK - 1);
  int b = idx >> 18;
  float a = -__expf(A_log[d * NST + n]);
  float h = 0.f, ap = 1.f;
  int t = b * SEQ + c * CHK;
#pragma unroll 4
  for (int l = 0; l < CHK; ++l, ++t) {
    float dv = delta[(size_t)t * DI + d];
    float xv = xc[(size_t)t * DI + d];
    float Bv = xdbl[(size_t)t * XD + DTR + n];
    float dA = __expf(dv * a);
    ap *= dA;
    h = fmaf(dA, h, dv * xv * Bv);
  }
  hend[idx] = h;
  aprod[idx] = ap;
}

// ---------------------------------------------------------------------------
// Chunked selective scan, pass 2: compose summaries, replay, gate, bf16 y.
// ---------------------------------------------------------------------------
__global__ __launch_bounds__(256) void scan2_k(
    const float* __restrict__ delta, const float* __restrict__ xc,
    const float* __restrict__ xdbl, const unsigned short* __restrict__ zbf,
    const float* __restrict__ A_log, const float* __restrict__ Dsk,
    const float* __restrict__ hend, const float* __restrict__ aprod,
    unsigned short* __restrict__ y) {
  int idx = blockIdx.x * 256 + threadIdx.x;
  int n = idx & 15;
  int d = (idx >> 4) & (DI - 1);
  int c = (idx >> 15) & (NCHK - 1);
  int b = idx >> 18;
  float a = -__expf(A_log[d * NST + n]);
  float dskip = Dsk[d];
  float h = 0.f;
  int base = idx & ~((NCHK - 1) << 15);
  for (int pc = 0; pc < c; ++pc) {
    int pi = base | (pc << 15);
    h = fmaf(aprod[pi], h, hend[pi]);
  }
  int t = b * SEQ + c * CHK;
#pragma unroll 2
  for (int l = 0; l < CHK; ++l, ++t) {
    float dv = delta[(size_t)t * DI + d];
    float xv = xc[(size_t)t * DI + d];
    float Bv = xdbl[(size_t)t * XD + DTR + n];
    float Cv = xdbl[(size_t)t * XD + DTR + NST + n];
    float dA = __expf(dv * a);
    h = fmaf(dA, h, dv * xv * Bv);
    float contrib = h * Cv;
    contrib += __shfl_xor(contrib, 1);
    contrib += __shfl_xor(contrib, 2);
    contrib += __shfl_xor(contrib, 4);
    contrib += __shfl_xor(contrib, 8);
    if (n == 0) {
      float zv = b2f(zbf[(size_t)t * DI + d]);
      float sig = zv / (1.f + __expf(-zv));
      y[(size_t)t * DI + d] = f2b((contrib + xv * dskip) * sig);
    }
  }
}

// ---------------------------------------------------------------------------
extern "C" void kernel_launch(void* const* d_in, const int* in_sizes, int n_in,
                              void* d_out, int out_size, void* d_ws,
                              size_t ws_size, hipStream_t stream) {
  const float* x_in      = (const float*)d_in[0];
  const float* ln0_w     = (const float*)d_in[1];
  const float* ln0_b     = (const float*)d_in[2];
  const float* ln1_w     = (const float*)d_in[3];
  const float* ln1_b     = (const float*)d_in[4];
  const float* ln2_w     = (const float*)d_in[5];
  const float* ln2_b     = (const float*)d_in[6];
  const float* in_proj_w = (const float*)d_in[7];
  const float* conv_w    = (const float*)d_in[8];
  const float* conv_b    = (const float*)d_in[9];
  const float* x_proj_w  = (const float*)d_in[10];
  const float* dt_proj_w = (const float*)d_in[11];
  const float* dt_proj_b = (const float*)d_in[12];
  const float* A_log     = (const float*)d_in[13];
  const float* D_skip    = (const float*)d_in[14];
  const float* out_proj_w= (const float*)d_in[15];
  const float* ffn_w1    = (const float*)d_in[16];
  const float* ffn_b1    = (const float*)d_in[17];
  const float* ffn_w2    = (const float*)d_in[18];
  const float* ffn_b2    = (const float*)d_in[19];
  float* out = (float*)d_out;

  // Workspace layout (floats), liveness-aliased; total 20.12M floats = 80.5 MB
  float* ws    = (float*)d_ws;
  float* xws   = ws;                     // [T,DM] fp32 residual          2.097M
  float* big   = xws + 2097152;          // xh fp32 / ybf bf16 / hbf bf16 4.194M
  float* zbf_f = big + 4194304;          // [T,DI] bf16 z-gate            2.097M
  float* xcws  = zbf_f + 2097152;        // [T,DI] fp32 conv+silu out     4.194M
  float* xdbl  = xcws + 4194304;         // [T,96] fp32                   0.197M
  float* dws   = xdbl + 196608;          // [T,DI] fp32 delta             4.194M
  float* ubf_f = dws + 4194304;          // [T,DM] bf16 LN out            1.049M
  float* wbf_f = ubf_f + 1048576;        // staging region                2.097M
  // aliases (timeline-checked):
  float*          xh   = big;                    // dies after conv
  unsigned short* ybf  = (unsigned short*)big;   // scan2 -> out_proj
  unsigned short* hbf  = (unsigned short*)big;   // ffn1 -> ffn2 [T,FFN] bf16
  unsigned short* zbf  = (unsigned short*)zbf_f;
  unsigned short* ubf  = (unsigned short*)ubf_f;
  unsigned short* xcb  = (unsigned short*)dws;   // [T,DI] bf16, dies before dt_proj
  // wbf region timeline: in_proj w (2.097M) -> {xproj partials 1.573M | wpb |
  // dtb | dwb} -> {hend+aprod 1.049M} -> out_proj w (1.049M) -> ffn w (2.097M)
  unsigned short* wbf  = (unsigned short*)wbf_f;
  float* part  = wbf_f;                          // [8][T,96] fp32 = 1.573M
  unsigned short* wpb = (unsigned short*)(wbf_f + 1572864);  // x_proj_w bf16 (98304 fl)
  unsigned short* dtb = (unsigned short*)(wbf_f + 1671168);  // dt bf16 [T,64] (65536 fl)
  unsigned short* dwb = (unsigned short*)(wbf_f + 1736704);  // dt_proj_w bf16 (65536 fl)
  float* hend  = wbf_f;                  // [524288]
  float* aprod = wbf_f + 524288;         // [524288]

  // 1: convert in_proj_w -> bf16 (4096x1024)
  f2b_k<<<(4096 * 1024) / 1024, 256, 0, stream>>>(in_proj_w, wbf);
  // 2-3: LN0 (fp32), LN1 (bf16)
  ln_k<<<T_TOK, 256, 0, stream>>>(x_in, ln0_w, ln0_b, xws);
  ln_bf_k<<<T_TOK, 256, 0, stream>>>(xws, ln1_w, ln1_b, ubf);
  // 4-5: in_proj x-half -> xh fp32 ; z-half -> zbf bf16
  {
    dim3 g(DI / 128, T_TOK / 128);
    gemm_bf16<<<g, 256, 0, stream>>>(ubf, DM, wbf, DM, xh, DI, DM, 0, nullptr, nullptr);
    gemm_bf16<<<g, 256, 0, stream>>>(ubf, DM, wbf + (size_t)DI * DM, DM, zbf, DI, DM, 1,
                                     nullptr, nullptr);
  }
  // 6: causal conv + silu -> xc fp32 + xcb bf16
  conv_silu_k<<<(T_TOK * DI) / 256, 256, 0, stream>>>(xh, conv_w, conv_b, xcws, xcb);
  // 7: x_proj weights -> bf16; dt_proj weights -> bf16
  f2b_k<<<(XD * DI) / 1024, 256, 0, stream>>>(x_proj_w, wpb);
  f2b_k<<<(DI * DTR) / 1024, 256, 0, stream>>>(dt_proj_w, dwb);
  // 8: x_proj split-K MFMA + reduce -> xdbl fp32, dtb bf16
  {
    dim3 g(T_TOK / 64, SPLITK);
    xproj_k<<<g, 256, 0, stream>>>(xcb, wpb, part);
    xreduce_k<<<(T_TOK * XD) / 256, 256, 0, stream>>>(part, xdbl, dtb);
  }
  // 9: dt_proj + softplus (bf16 MFMA) -> delta fp32
  {
    dim3 g(DI / 128, T_TOK / 128);
    gemm_bf16<<<g, 256, 0, stream>>>(dtb, DTR, dwb, DTR, dws, DI, DTR, 5,
                                     dt_proj_b, nullptr);
  }
  // 10-11: chunked scan (hend/aprod alias dead xproj partials)
  scan1_k<<<(2 * DI * NST * NCHK) / 256, 256, 0, stream>>>(dws, xcws, xdbl, A_log,
                                                           hend, aprod);
  scan2_k<<<(2 * DI * NST * NCHK) / 256, 256, 0, stream>>>(dws, xcws, xdbl, zbf,
                                                           A_log, D_skip, hend, aprod,
                                                           ybf);
  // 12-13: out_proj (bf16) + residual -> xws
  f2b_k<<<(DM * DI) / 1024, 256, 0, stream>>>(out_proj_w, wbf);
  {
    dim3 g(DM / 128, T_TOK / 128);
    gemm_bf16<<<g, 256, 0, stream>>>(ybf, DI, wbf, DI, xws, DM, DI, 3, nullptr, xws);
  }
  // 14: LN2 -> bf16
  ln_bf_k<<<T_TOK, 256, 0, stream>>>(xws, ln2_w, ln2_b, ubf);
  // 15-16: ffn1 + bias + gelu -> hbf bf16
  f2b_k<<<(FFN * DM) / 1024, 256, 0, stream>>>(ffn_w1, wbf);
  {
    dim3 g(FFN / 128, T_TOK / 128);
    gemm_bf16<<<g, 256, 0, stream>>>(ubf, DM, wbf, DM, hbf, FFN, DM, 2, ffn_b1, nullptr);
  }
  // 17-18: ffn2 + bias + residual -> d_out fp32
  f2b_k<<<(DM * FFN) / 1024, 256, 0, stream>>>(ffn_w2, wbf);
  {
    dim3 g(DM / 128, T_TOK / 128);
    gemm_bf16<<<g, 256, 0, stream>>>(hbf, FFN, wbf, FFN, out, DM, FFN, 4, ffn_b2, xws);
  }
}

// Round 4
// 627.412 us; speedup vs baseline: 3.4192x; 1.2621x over previous
//
#include <hip/hip_runtime.h>
#include <math.h>

// Problem constants (match reference)
#define T_TOK 2048   // B*L
#define SEQ   1024   // L
#define DM    1024   // d_model
#define DI    2048   // d_inner
#define FFN   4096
#define NST   16     // d_state
#define DTR   64     // dt_rank
#define XD    96     // dt_rank + 2*d_state
#define CHK   128    // scan chunk length
#define NCHK  8      // chunks per sequence
#define SPLITK 8     // x_proj K-splits (K chunk = 256)

typedef __attribute__((ext_vector_type(8))) short short8;
typedef __attribute__((ext_vector_type(4))) float floatx4;

__device__ __forceinline__ unsigned short f2b(float f) {
  unsigned u = __float_as_uint(f);
  unsigned r = (u + 0x7fff + ((u >> 16) & 1)) >> 16;  // RNE
  return (unsigned short)r;
}
__device__ __forceinline__ float b2f(unsigned short s) {
  return __uint_as_float(((unsigned)s) << 16);
}

// async global->LDS, 16 B per lane. lds must be the wave-uniform base
// (lane 0's destination); HW adds lane*16.
typedef const __attribute__((address_space(1))) unsigned int g_uint;
typedef __attribute__((address_space(3))) unsigned int l_uint;
__device__ __forceinline__ void async16(void* lds, const void* g) {
  __builtin_amdgcn_global_load_lds((g_uint*)(size_t)g,
                                   (l_uint*)(unsigned)(size_t)lds, 16, 0, 0);
}

// ---------------------------------------------------------------------------
// fp32 -> bf16 bulk convert (n multiple of 1024); 4 elems/thread
// ---------------------------------------------------------------------------
__global__ __launch_bounds__(256) void f2b_k(const float* __restrict__ in,
                                             unsigned short* __restrict__ out) {
  int i = blockIdx.x * 256 + threadIdx.x;
  float4 v = ((const float4*)in)[i];
  ushort4 o;
  o.x = f2b(v.x); o.y = f2b(v.y); o.z = f2b(v.z); o.w = f2b(v.w);
  ((ushort4*)out)[i] = o;
}

// ---------------------------------------------------------------------------
// LayerNorm fp32 out: one block per token, 256 threads x 4 elems = 1024 dims
// ---------------------------------------------------------------------------
__global__ __launch_bounds__(256) void ln_k(const float* __restrict__ in,
                                            const float* __restrict__ w,
                                            const float* __restrict__ bb,
                                            float* __restrict__ out) {
  int t = blockIdx.x;
  int tid = threadIdx.x;
  const float* row = in + (size_t)t * DM;
  float4 v = *(const float4*)(row + tid * 4);
  float s = v.x + v.y + v.z + v.w;
  __shared__ float sm[2][4];
  for (int off = 32; off > 0; off >>= 1) s += __shfl_down(s, off, 64);
  int wv = tid >> 6, ln = tid & 63;
  if (ln == 0) sm[0][wv] = s;
  __syncthreads();
  float mu = (sm[0][0] + sm[0][1] + sm[0][2] + sm[0][3]) * (1.0f / DM);
  float d0 = v.x - mu, d1 = v.y - mu, d2 = v.z - mu, d3 = v.w - mu;
  float sq = d0 * d0 + d1 * d1 + d2 * d2 + d3 * d3;
  for (int off = 32; off > 0; off >>= 1) sq += __shfl_down(sq, off, 64);
  if (ln == 0) sm[1][wv] = sq;
  __syncthreads();
  float var = (sm[1][0] + sm[1][1] + sm[1][2] + sm[1][3]) * (1.0f / DM);
  float rs = rsqrtf(var + 1e-5f);
  float4 w4 = *(const float4*)(w + tid * 4);
  float4 b4 = *(const float4*)(bb + tid * 4);
  float4 o;
  o.x = d0 * rs * w4.x + b4.x;
  o.y = d1 * rs * w4.y + b4.y;
  o.z = d2 * rs * w4.z + b4.z;
  o.w = d3 * rs * w4.w + b4.w;
  *(float4*)(out + (size_t)t * DM + tid * 4) = o;
}

// LayerNorm bf16 out
__global__ __launch_bounds__(256) void ln_bf_k(const float* __restrict__ in,
                                               const float* __restrict__ w,
                                               const float* __restrict__ bb,
                                               unsigned short* __restrict__ out) {
  int t = blockIdx.x;
  int tid = threadIdx.x;
  const float* row = in + (size_t)t * DM;
  float4 v = *(const float4*)(row + tid * 4);
  float s = v.x + v.y + v.z + v.w;
  __shared__ float sm[2][4];
  for (int off = 32; off > 0; off >>= 1) s += __shfl_down(s, off, 64);
  int wv = tid >> 6, ln = tid & 63;
  if (ln == 0) sm[0][wv] = s;
  __syncthreads();
  float mu = (sm[0][0] + sm[0][1] + sm[0][2] + sm[0][3]) * (1.0f / DM);
  float d0 = v.x - mu, d1 = v.y - mu, d2 = v.z - mu, d3 = v.w - mu;
  float sq = d0 * d0 + d1 * d1 + d2 * d2 + d3 * d3;
  for (int off = 32; off > 0; off >>= 1) sq += __shfl_down(sq, off, 64);
  if (ln == 0) sm[1][wv] = sq;
  __syncthreads();
  float var = (sm[1][0] + sm[1][1] + sm[1][2] + sm[1][3]) * (1.0f / DM);
  float rs = rsqrtf(var + 1e-5f);
  float4 w4 = *(const float4*)(w + tid * 4);
  float4 b4 = *(const float4*)(bb + tid * 4);
  ushort4 o;
  o.x = f2b(d0 * rs * w4.x + b4.x);
  o.y = f2b(d1 * rs * w4.y + b4.y);
  o.z = f2b(d2 * rs * w4.z + b4.z);
  o.w = f2b(d3 * rs * w4.w + b4.w);
  *(ushort4*)(out + (size_t)t * DM + tid * 4) = o;
}

// ---------------------------------------------------------------------------
// bf16 MFMA GEMM (NT): C[m,n] = sum_k A[m,k]*W[n,k].  128x128 tile, 4 waves,
// 16x16x32 MFMA, global_load_lds staging.  Split-K via blockIdx.z: each z
// does Kc of K starting at z*Kc.
// epi: 0 fp32 | 1 bf16 | 2 gelu(acc+bias) bf16 | 3 acc+res fp32
//      4 acc+bias+res fp32 | 5 softplus(acc+bias) fp32 | 6 split-K fp32 partial
// partial base: z in {0,1} -> p0 + z*T*ldc ; z in {2,3} -> p1 + (z-2)*T*ldc
// ---------------------------------------------------------------------------
__global__ __launch_bounds__(256) void gemm_bf16(
    const unsigned short* __restrict__ A, int lda,
    const unsigned short* __restrict__ Bw, int ldb,
    void* __restrict__ Cout, int ldc, int Kc, int epi,
    const float* __restrict__ bias, const float* __restrict__ res,
    float* __restrict__ p0, float* __restrict__ p1) {
  __shared__ __align__(16) unsigned short As[4][128][8];  // [k-slab][row][8k]
  __shared__ __align__(16) unsigned short Bs[4][128][8];
  int tid = threadIdx.x;
  int lane = tid & 63, wv = tid >> 6;
  int wr = wv >> 1, wc = wv & 1;
  int m0 = blockIdx.y * 128, n0 = blockIdx.x * 128;
  int ml = lane & 15, kq = lane >> 4;
  int kstart = blockIdx.z * Kc;
  floatx4 acc[4][4] = {};
  for (int k0 = kstart; k0 < kstart + Kc; k0 += 32) {
#pragma unroll
    for (int i = 0; i < 2; ++i) {
      int c = tid + i * 256;
      int row = c & 127, slab = c >> 7;          // per-lane
      int cw = wv * 64 + i * 256;
      int row0 = cw & 127, slab0 = cw >> 7;      // wave-uniform
      async16(&As[slab0][row0][0], A + (size_t)(m0 + row) * lda + k0 + slab * 8);
      async16(&Bs[slab0][row0][0], Bw + (size_t)(n0 + row) * ldb + k0 + slab * 8);
    }
    __syncthreads();
    short8 af[4], bfr[4];
#pragma unroll
    for (int i = 0; i < 4; ++i)
      af[i] = *(const short8*)&As[kq][wr * 64 + i * 16 + ml][0];
#pragma unroll
    for (int j = 0; j < 4; ++j)
      bfr[j] = *(const short8*)&Bs[kq][wc * 64 + j * 16 + ml][0];
#pragma unroll
    for (int i = 0; i < 4; ++i)
#pragma unroll
      for (int j = 0; j < 4; ++j)
        acc[i][j] =
            __builtin_amdgcn_mfma_f32_16x16x32_bf16(af[i], bfr[j], acc[i][j], 0, 0, 0);
    __syncthreads();
  }
  float* pdst = nullptr;
  if (epi == 6) {
    pdst = (blockIdx.z & 2) ? p1 : p0;
    pdst += (size_t)(blockIdx.z & 1) * T_TOK * ldc;
  }
  // epilogue: D row = (lane>>4)*4 + r, col = lane&15
#pragma unroll
  for (int i = 0; i < 4; ++i) {
    int gm = m0 + wr * 64 + i * 16 + kq * 4;
#pragma unroll
    for (int j = 0; j < 4; ++j) {
      int gn = n0 + wc * 64 + j * 16 + ml;
#pragma unroll
      for (int r = 0; r < 4; ++r) {
        float v = acc[i][j][r];
        size_t off = (size_t)(gm + r) * ldc + gn;
        if (epi == 0) {
          ((float*)Cout)[off] = v;
        } else if (epi == 1) {
          ((unsigned short*)Cout)[off] = f2b(v);
        } else if (epi == 2) {
          float x = v + bias[gn];
          float u = 0.7978845608028654f * (x + 0.044715f * x * x * x);
          ((unsigned short*)Cout)[off] = f2b(0.5f * x * (1.f + tanhf(u)));
        } else if (epi == 3) {
          ((float*)Cout)[off] = v + res[off];
        } else if (epi == 4) {
          ((float*)Cout)[off] = v + bias[gn] + res[off];
        } else if (epi == 5) {
          float x = v + bias[gn];
          ((float*)Cout)[off] = (x > 20.f) ? x : log1pf(__expf(x));
        } else {
          pdst[off] = v;
        }
      }
    }
  }
}

// reduce 4 split-K partials (+bias +res) -> out fp32.  N must be 1024 (=DM).
__global__ __launch_bounds__(256) void reduce4_k(const float* __restrict__ p0,
                                                 const float* __restrict__ p1,
                                                 float* __restrict__ out,
                                                 const float* __restrict__ bias,
                                                 const float* __restrict__ res) {
  int i = blockIdx.x * 256 + threadIdx.x;  // < T_TOK*DM
  const size_t TN = (size_t)T_TOK * DM;
  float s = p0[i] + p0[i + TN] + p1[i] + p1[i + TN];
  if (bias) s += bias[i & (DM - 1)];
  if (res) s += res[i];
  out[i] = s;
}

// ---------------------------------------------------------------------------
// x_proj split-K bf16 MFMA: part[ks][m][n] = sum_{k chunk} xcb[m,k]*W[n,k]
// ---------------------------------------------------------------------------
__global__ __launch_bounds__(256) void xproj_k(
    const unsigned short* __restrict__ xcb, const unsigned short* __restrict__ wpb,
    float* __restrict__ part) {
  __shared__ __align__(16) unsigned short As[4][64][8];
  __shared__ __align__(16) unsigned short Bs[32][96][8];
  int tid = threadIdx.x;
  int lane = tid & 63, wv = tid >> 6;
  int ml = lane & 15, kq = lane >> 4;
  int m0 = blockIdx.x * 64;
  int ks = blockIdx.y;
  int kbase = ks * 256;
  for (int e = tid; e < 3072; e += 256) {
    int row = e >> 5, slab = e & 31;
    *(int4*)&Bs[slab][row][0] = *(const int4*)(wpb + (size_t)row * DI + kbase + slab * 8);
  }
  floatx4 acc[6] = {};
  for (int s = 0; s < 8; ++s) {
    async16(&As[wv][0][0],
            xcb + (size_t)(m0 + lane) * DI + kbase + s * 32 + wv * 8);
    __syncthreads();
    short8 af = *(const short8*)&As[kq][wv * 16 + ml][0];
#pragma unroll
    for (int j = 0; j < 6; ++j) {
      short8 bf = *(const short8*)&Bs[s * 4 + kq][j * 16 + ml][0];
      acc[j] = __builtin_amdgcn_mfma_f32_16x16x32_bf16(af, bf, acc[j], 0, 0, 0);
    }
    __syncthreads();
  }
  float* dst = part + (size_t)ks * (T_TOK * XD);
#pragma unroll
  for (int j = 0; j < 6; ++j) {
    int gn = j * 16 + ml;
    int gm = m0 + wv * 16 + kq * 4;
#pragma unroll
    for (int r = 0; r < 4; ++r) dst[(size_t)(gm + r) * XD + gn] = acc[j][r];
  }
}

// reduce x_proj partials -> x_dbl fp32 [T,96]; dt part as bf16 [T,64]
__global__ __launch_bounds__(256) void xreduce_k(const float* __restrict__ part,
                                                 float* __restrict__ xdbl,
                                                 unsigned short* __restrict__ dtb) {
  int i = blockIdx.x * 256 + threadIdx.x;  // < T_TOK*XD
  float s = 0.f;
#pragma unroll
  for (int ks = 0; ks < SPLITK; ++ks) s += part[(size_t)ks * (T_TOK * XD) + i];
  xdbl[i] = s;
  int t = i / XD, c = i - t * XD;
  if (c < DTR) dtb[(size_t)t * DTR + c] = f2b(s);
}

// ---------------------------------------------------------------------------
// Causal depthwise conv (k=4) + bias + SiLU. Reads bf16 x-half of xz
// (row stride 2*DI). Emits fp32 (scan) + bf16 (x_proj).
// ---------------------------------------------------------------------------
__global__ __launch_bounds__(256) void conv_silu_k(
    const unsigned short* __restrict__ xzb, const float* __restrict__ cw,
    const float* __restrict__ cb, float* __restrict__ xc,
    unsigned short* __restrict__ xcb) {
  int idx = blockIdx.x * 256 + threadIdx.x;  // over T_TOK*DI
  int d = idx & (DI - 1);
  int t = idx >> 11;
  int l = t & (SEQ - 1);
  const unsigned short* base = xzb + (size_t)t * (2 * DI) + d;
  float4 w4 = *(const float4*)(cw + d * 4);
  float s = cb[d] + w4.w * b2f(base[0]);
  if (l >= 1) s = fmaf(w4.z, b2f(base[-(2 * DI)]), s);
  if (l >= 2) s = fmaf(w4.y, b2f(base[-2 * (2 * DI)]), s);
  if (l >= 3) s = fmaf(w4.x, b2f(base[-3 * (2 * DI)]), s);
  float y = s / (1.f + __expf(-s));  // silu
  xc[(size_t)t * DI + d] = y;
  xcb[(size_t)t * DI + d] = f2b(y);
}

// ---------------------------------------------------------------------------
// Chunked selective scan, pass 1: per-chunk (prod dA, local h_end).
// ---------------------------------------------------------------------------
__global__ __launch_bounds__(256) void scan1_k(
    const float* __restrict__ delta, const float* __restrict__ xc,
    const float* __restrict__ xdbl, const float* __restrict__ A_log,
    float* __restrict__ hend, float* __restrict__ aprod) {
  int idx = blockIdx.x * 256 + threadIdx.x;
  int n = idx & 15;
  int d = (idx >> 4) & (DI - 1);
  int c = (idx >> 15) & (NCHK - 1);
  int b = idx >> 18;
  float a = -__expf(A_log[d * NST + n]);
  float h = 0.f, ap = 1.f;
  int t = b * SEQ + c * CHK;
#pragma unroll 4
  for (int l = 0; l < CHK; ++l, ++t) {
    float dv = delta[(size_t)t * DI + d];
    float xv = xc[(size_t)t * DI + d];
    float Bv = xdbl[(size_t)t * XD + DTR + n];
    float dA = __expf(dv * a);
    ap *= dA;
    h = fmaf(dA, h, dv * xv * Bv);
  }
  hend[idx] = h;
  aprod[idx] = ap;
}

// ---------------------------------------------------------------------------
// Chunked selective scan, pass 2: compose summaries, replay, gate, bf16 y.
// z is read from xz (bf16, stride 2*DI, offset DI).
// ---------------------------------------------------------------------------
__global__ __launch_bounds__(256) void scan2_k(
    const float* __restrict__ delta, const float* __restrict__ xc,
    const float* __restrict__ xdbl, const unsigned short* __restrict__ xzb,
    const float* __restrict__ A_log, const float* __restrict__ Dsk,
    const float* __restrict__ hend, const float* __restrict__ aprod,
    unsigned short* __restrict__ y) {
  int idx = blockIdx.x * 256 + threadIdx.x;
  int n = idx & 15;
  int d = (idx >> 4) & (DI - 1);
  int c = (idx >> 15) & (NCHK - 1);
  int b = idx >> 18;
  float a = -__expf(A_log[d * NST + n]);
  float dskip = Dsk[d];
  float h = 0.f;
  int base = idx & ~((NCHK - 1) << 15);
  for (int pc = 0; pc < c; ++pc) {
    int pi = base | (pc << 15);
    h = fmaf(aprod[pi], h, hend[pi]);
  }
  int t = b * SEQ + c * CHK;
#pragma unroll 2
  for (int l = 0; l < CHK; ++l, ++t) {
    float dv = delta[(size_t)t * DI + d];
    float xv = xc[(size_t)t * DI + d];
    float Bv = xdbl[(size_t)t * XD + DTR + n];
    float Cv = xdbl[(size_t)t * XD + DTR + NST + n];
    float dA = __expf(dv * a);
    h = fmaf(dA, h, dv * xv * Bv);
    float contrib = h * Cv;
    contrib += __shfl_xor(contrib, 1);
    contrib += __shfl_xor(contrib, 2);
    contrib += __shfl_xor(contrib, 4);
    contrib += __shfl_xor(contrib, 8);
    if (n == 0) {
      float zv = b2f(xzb[(size_t)t * (2 * DI) + DI + d]);
      float sig = zv / (1.f + __expf(-zv));
      y[(size_t)t * DI + d] = f2b((contrib + xv * dskip) * sig);
    }
  }
}

// ---------------------------------------------------------------------------
extern "C" void kernel_launch(void* const* d_in, const int* in_sizes, int n_in,
                              void* d_out, int out_size, void* d_ws,
                              size_t ws_size, hipStream_t stream) {
  const float* x_in      = (const float*)d_in[0];
  const float* ln0_w     = (const float*)d_in[1];
  const float* ln0_b     = (const float*)d_in[2];
  const float* ln1_w     = (const float*)d_in[3];
  const float* ln1_b     = (const float*)d_in[4];
  const float* ln2_w     = (const float*)d_in[5];
  const float* ln2_b     = (const float*)d_in[6];
  const float* in_proj_w = (const float*)d_in[7];
  const float* conv_w    = (const float*)d_in[8];
  const float* conv_b    = (const float*)d_in[9];
  const float* x_proj_w  = (const float*)d_in[10];
  const float* dt_proj_w = (const float*)d_in[11];
  const float* dt_proj_b = (const float*)d_in[12];
  const float* A_log     = (const float*)d_in[13];
  const float* D_skip    = (const float*)d_in[14];
  const float* out_proj_w= (const float*)d_in[15];
  const float* ffn_w1    = (const float*)d_in[16];
  const float* ffn_b1    = (const float*)d_in[17];
  const float* ffn_w2    = (const float*)d_in[18];
  const float* ffn_b2    = (const float*)d_in[19];
  float* out = (float*)d_out;

  // Workspace layout (floats), liveness-aliased; total 20.12M floats = 80.5 MB
  float* ws    = (float*)d_ws;
  float* xws   = ws;                     // [T,DM] fp32 residual          2.097M
  float* big   = xws + 2097152;          // xzb bf16 [T,4096] / hbf bf16  4.194M
  float* r2    = big + 4194304;          // ybf bf16 [T,DI]               2.097M
  float* xcws  = r2 + 2097152;           // xc fp32 / split-K partials    4.194M
  float* xdbl  = xcws + 4194304;         // [T,96] fp32                   0.197M
  float* dws   = xdbl + 196608;          // xcb bf16 / delta fp32 / parts 4.194M
  float* ubf_f = dws + 4194304;          // [T,DM] bf16 LN out            1.049M
  float* wbf_f = ubf_f + 1048576;        // staging region                2.097M
  // aliases (timeline-checked):
  unsigned short* xzb  = (unsigned short*)big;   // in_proj out, dies after scan2
  unsigned short* hbf  = (unsigned short*)big;   // ffn1 -> ffn2 [T,FFN] bf16
  unsigned short* ybf  = (unsigned short*)r2;    // scan2 -> out_proj
  unsigned short* ubf  = (unsigned short*)ubf_f;
  unsigned short* xcb  = (unsigned short*)dws;   // conv bf16, dies before dt_proj
  unsigned short* wbf  = (unsigned short*)wbf_f;
  float* part  = wbf_f;                          // xproj partials [8][T,96] 1.573M
  unsigned short* wpb = (unsigned short*)(wbf_f + 1572864);  // x_proj_w bf16
  unsigned short* dtb = (unsigned short*)(wbf_f + 1671168);  // dt bf16 [T,64]
  unsigned short* dwb = (unsigned short*)(wbf_f + 1736704);  // dt_proj_w bf16
  float* hend  = wbf_f;                  // [524288]
  float* aprod = wbf_f + 524288;         // [524288]

  // 1: convert in_proj_w -> bf16 (4096x1024)
  f2b_k<<<(4096 * 1024) / 1024, 256, 0, stream>>>(in_proj_w, wbf);
  // 2-3: LN0 (fp32), LN1 (bf16)
  ln_k<<<T_TOK, 256, 0, stream>>>(x_in, ln0_w, ln0_b, xws);
  ln_bf_k<<<T_TOK, 256, 0, stream>>>(xws, ln1_w, ln1_b, ubf);
  // 4: in_proj, single dispatch N=4096 -> xzb bf16 (512 blocks)
  {
    dim3 g((2 * DI) / 128, T_TOK / 128, 1);
    gemm_bf16<<<g, 256, 0, stream>>>(ubf, DM, wbf, DM, xzb, 2 * DI, DM, 1,
                                     nullptr, nullptr, nullptr, nullptr);
  }
  // 5: causal conv + silu (bf16 in) -> xc fp32 + xcb bf16
  conv_silu_k<<<(T_TOK * DI) / 256, 256, 0, stream>>>(xzb, conv_w, conv_b, xcws, xcb);
  // 6: x_proj / dt_proj weights -> bf16
  f2b_k<<<(XD * DI) / 1024, 256, 0, stream>>>(x_proj_w, wpb);
  f2b_k<<<(DI * DTR) / 1024, 256, 0, stream>>>(dt_proj_w, dwb);
  // 7: x_proj split-K MFMA + reduce -> xdbl fp32, dtb bf16
  {
    dim3 g(T_TOK / 64, SPLITK);
    xproj_k<<<g, 256, 0, stream>>>(xcb, wpb, part);
    xreduce_k<<<(T_TOK * XD) / 256, 256, 0, stream>>>(part, xdbl, dtb);
  }
  // 8: dt_proj + softplus (bf16 MFMA) -> delta fp32
  {
    dim3 g(DI / 128, T_TOK / 128, 1);
    gemm_bf16<<<g, 256, 0, stream>>>(dtb, DTR, dwb, DTR, dws, DI, DTR, 5,
                                     dt_proj_b, nullptr, nullptr, nullptr);
  }
  // 9-10: chunked scan (hend/aprod alias dead xproj partials)
  scan1_k<<<(2 * DI * NST * NCHK) / 256, 256, 0, stream>>>(dws, xcws, xdbl, A_log,
                                                           hend, aprod);
  scan2_k<<<(2 * DI * NST * NCHK) / 256, 256, 0, stream>>>(dws, xcws, xdbl, xzb,
                                                           A_log, D_skip, hend, aprod,
                                                           ybf);
  // 11: out_proj split-K x4 (512 blocks) + reduce(+res) -> xws
  f2b_k<<<(DM * DI) / 1024, 256, 0, stream>>>(out_proj_w, wbf);
  {
    dim3 g(DM / 128, T_TOK / 128, 4);
    gemm_bf16<<<g, 256, 0, stream>>>(ybf, DI, wbf, DI, nullptr, DM, DI / 4, 6,
                                     nullptr, nullptr, xcws, dws);
    reduce4_k<<<(T_TOK * DM) / 256, 256, 0, stream>>>(xcws, dws, xws, nullptr, xws);
  }
  // 12: LN2 -> bf16
  ln_bf_k<<<T_TOK, 256, 0, stream>>>(xws, ln2_w, ln2_b, ubf);
  // 13: ffn1 + bias + gelu -> hbf bf16 (512 blocks)
  f2b_k<<<(FFN * DM) / 1024, 256, 0, stream>>>(ffn_w1, wbf);
  {
    dim3 g(FFN / 128, T_TOK / 128, 1);
    gemm_bf16<<<g, 256, 0, stream>>>(ubf, DM, wbf, DM, hbf, FFN, DM, 2,
                                     ffn_b1, nullptr, nullptr, nullptr);
  }
  // 14: ffn2 split-K x4 (512 blocks) + reduce(+bias+res) -> d_out
  f2b_k<<<(DM * FFN) / 1024, 256, 0, stream>>>(ffn_w2, wbf);
  {
    dim3 g(DM / 128, T_TOK / 128, 4);
    gemm_bf16<<<g, 256, 0, stream>>>(hbf, FFN, wbf, FFN, nullptr, DM, FFN / 4, 6,
                                     nullptr, nullptr, dws, xcws);
    reduce4_k<<<(T_TOK * DM) / 256, 256, 0, stream>>>(dws, xcws, out, ffn_b2, xws);
  }
}

// Round 5
// 566.089 us; speedup vs baseline: 3.7895x; 1.1083x over previous
//
#include <hip/hip_runtime.h>
#include <math.h>

// Problem constants (match reference)
#define T_TOK 2048   // B*L
#define SEQ   1024   // L
#define DM    1024   // d_model
#define DI    2048   // d_inner
#define FFN   4096
#define NST   16     // d_state
#define DTR   64     // dt_rank
#define XD    96     // dt_rank + 2*d_state
#define CHK   64     // scan chunk length
#define NCHK  16     // chunks per sequence
#define SPLITK 8     // x_proj K-splits (K chunk = 256)

typedef __attribute__((ext_vector_type(8))) short short8;
typedef __attribute__((ext_vector_type(4))) float floatx4;

__device__ __forceinline__ unsigned short f2b(float f) {
  unsigned u = __float_as_uint(f);
  unsigned r = (u + 0x7fff + ((u >> 16) & 1)) >> 16;  // RNE
  return (unsigned short)r;
}
__device__ __forceinline__ float b2f(unsigned short s) {
  return __uint_as_float(((unsigned)s) << 16);
}

// async global->LDS, 16 B per lane. lds must be the wave-uniform base
// (lane 0's destination); HW adds lane*16.
typedef const __attribute__((address_space(1))) unsigned int g_uint;
typedef __attribute__((address_space(3))) unsigned int l_uint;
__device__ __forceinline__ void async16(void* lds, const void* g) {
  __builtin_amdgcn_global_load_lds((g_uint*)(size_t)g,
                                   (l_uint*)(unsigned)(size_t)lds, 16, 0, 0);
}

// ---------------------------------------------------------------------------
// fp32 -> bf16 bulk convert (n multiple of 1024); 4 elems/thread
// ---------------------------------------------------------------------------
__global__ __launch_bounds__(256) void f2b_k(const float* __restrict__ in,
                                             unsigned short* __restrict__ out) {
  int i = blockIdx.x * 256 + threadIdx.x;
  float4 v = ((const float4*)in)[i];
  ushort4 o;
  o.x = f2b(v.x); o.y = f2b(v.y); o.z = f2b(v.z); o.w = f2b(v.w);
  ((ushort4*)out)[i] = o;
}

// ---------------------------------------------------------------------------
// LayerNorm fp32 out: one block per token, 256 threads x 4 elems = 1024 dims
// ---------------------------------------------------------------------------
__global__ __launch_bounds__(256) void ln_k(const float* __restrict__ in,
                                            const float* __restrict__ w,
                                            const float* __restrict__ bb,
                                            float* __restrict__ out) {
  int t = blockIdx.x;
  int tid = threadIdx.x;
  const float* row = in + (size_t)t * DM;
  float4 v = *(const float4*)(row + tid * 4);
  float s = v.x + v.y + v.z + v.w;
  __shared__ float sm[2][4];
  for (int off = 32; off > 0; off >>= 1) s += __shfl_down(s, off, 64);
  int wv = tid >> 6, ln = tid & 63;
  if (ln == 0) sm[0][wv] = s;
  __syncthreads();
  float mu = (sm[0][0] + sm[0][1] + sm[0][2] + sm[0][3]) * (1.0f / DM);
  float d0 = v.x - mu, d1 = v.y - mu, d2 = v.z - mu, d3 = v.w - mu;
  float sq = d0 * d0 + d1 * d1 + d2 * d2 + d3 * d3;
  for (int off = 32; off > 0; off >>= 1) sq += __shfl_down(sq, off, 64);
  if (ln == 0) sm[1][wv] = sq;
  __syncthreads();
  float var = (sm[1][0] + sm[1][1] + sm[1][2] + sm[1][3]) * (1.0f / DM);
  float rs = rsqrtf(var + 1e-5f);
  float4 w4 = *(const float4*)(w + tid * 4);
  float4 b4 = *(const float4*)(bb + tid * 4);
  float4 o;
  o.x = d0 * rs * w4.x + b4.x;
  o.y = d1 * rs * w4.y + b4.y;
  o.z = d2 * rs * w4.z + b4.z;
  o.w = d3 * rs * w4.w + b4.w;
  *(float4*)(out + (size_t)t * DM + tid * 4) = o;
}

// LayerNorm bf16 out
__global__ __launch_bounds__(256) void ln_bf_k(const float* __restrict__ in,
                                               const float* __restrict__ w,
                                               const float* __restrict__ bb,
                                               unsigned short* __restrict__ out) {
  int t = blockIdx.x;
  int tid = threadIdx.x;
  const float* row = in + (size_t)t * DM;
  float4 v = *(const float4*)(row + tid * 4);
  float s = v.x + v.y + v.z + v.w;
  __shared__ float sm[2][4];
  for (int off = 32; off > 0; off >>= 1) s += __shfl_down(s, off, 64);
  int wv = tid >> 6, ln = tid & 63;
  if (ln == 0) sm[0][wv] = s;
  __syncthreads();
  float mu = (sm[0][0] + sm[0][1] + sm[0][2] + sm[0][3]) * (1.0f / DM);
  float d0 = v.x - mu, d1 = v.y - mu, d2 = v.z - mu, d3 = v.w - mu;
  float sq = d0 * d0 + d1 * d1 + d2 * d2 + d3 * d3;
  for (int off = 32; off > 0; off >>= 1) sq += __shfl_down(sq, off, 64);
  if (ln == 0) sm[1][wv] = sq;
  __syncthreads();
  float var = (sm[1][0] + sm[1][1] + sm[1][2] + sm[1][3]) * (1.0f / DM);
  float rs = rsqrtf(var + 1e-5f);
  float4 w4 = *(const float4*)(w + tid * 4);
  float4 b4 = *(const float4*)(bb + tid * 4);
  ushort4 o;
  o.x = f2b(d0 * rs * w4.x + b4.x);
  o.y = f2b(d1 * rs * w4.y + b4.y);
  o.z = f2b(d2 * rs * w4.z + b4.z);
  o.w = f2b(d3 * rs * w4.w + b4.w);
  *(ushort4*)(out + (size_t)t * DM + tid * 4) = o;
}

// ---------------------------------------------------------------------------
// bf16 MFMA GEMM (NT): C[m,n] = sum_k A[m,k]*W[n,k].  128x128 tile, 4 waves,
// 16x16x32 MFMA, global_load_lds staging.  Split-K via blockIdx.z.
// epi: 0 fp32 | 1 bf16 | 2 gelu(acc+bias) bf16 | 3 acc+res fp32
//      4 acc+bias+res fp32 | 5 softplus(acc+bias) fp32 | 6 split-K fp32 partial
// ---------------------------------------------------------------------------
__global__ __launch_bounds__(256) void gemm_bf16(
    const unsigned short* __restrict__ A, int lda,
    const unsigned short* __restrict__ Bw, int ldb,
    void* __restrict__ Cout, int ldc, int Kc, int epi,
    const float* __restrict__ bias, const float* __restrict__ res,
    float* __restrict__ p0, float* __restrict__ p1) {
  __shared__ __align__(16) unsigned short As[4][128][8];  // [k-slab][row][8k]
  __shared__ __align__(16) unsigned short Bs[4][128][8];
  int tid = threadIdx.x;
  int lane = tid & 63, wv = tid >> 6;
  int wr = wv >> 1, wc = wv & 1;
  int m0 = blockIdx.y * 128, n0 = blockIdx.x * 128;
  int ml = lane & 15, kq = lane >> 4;
  int kstart = blockIdx.z * Kc;
  floatx4 acc[4][4] = {};
  for (int k0 = kstart; k0 < kstart + Kc; k0 += 32) {
#pragma unroll
    for (int i = 0; i < 2; ++i) {
      int c = tid + i * 256;
      int row = c & 127, slab = c >> 7;          // per-lane
      int cw = wv * 64 + i * 256;
      int row0 = cw & 127, slab0 = cw >> 7;      // wave-uniform
      async16(&As[slab0][row0][0], A + (size_t)(m0 + row) * lda + k0 + slab * 8);
      async16(&Bs[slab0][row0][0], Bw + (size_t)(n0 + row) * ldb + k0 + slab * 8);
    }
    __syncthreads();
    short8 af[4], bfr[4];
#pragma unroll
    for (int i = 0; i < 4; ++i)
      af[i] = *(const short8*)&As[kq][wr * 64 + i * 16 + ml][0];
#pragma unroll
    for (int j = 0; j < 4; ++j)
      bfr[j] = *(const short8*)&Bs[kq][wc * 64 + j * 16 + ml][0];
#pragma unroll
    for (int i = 0; i < 4; ++i)
#pragma unroll
      for (int j = 0; j < 4; ++j)
        acc[i][j] =
            __builtin_amdgcn_mfma_f32_16x16x32_bf16(af[i], bfr[j], acc[i][j], 0, 0, 0);
    __syncthreads();
  }
  float* pdst = nullptr;
  if (epi == 6) {
    pdst = (blockIdx.z & 2) ? p1 : p0;
    pdst += (size_t)(blockIdx.z & 1) * T_TOK * ldc;
  }
  // epilogue: D row = (lane>>4)*4 + r, col = lane&15
#pragma unroll
  for (int i = 0; i < 4; ++i) {
    int gm = m0 + wr * 64 + i * 16 + kq * 4;
#pragma unroll
    for (int j = 0; j < 4; ++j) {
      int gn = n0 + wc * 64 + j * 16 + ml;
#pragma unroll
      for (int r = 0; r < 4; ++r) {
        float v = acc[i][j][r];
        size_t off = (size_t)(gm + r) * ldc + gn;
        if (epi == 0) {
          ((float*)Cout)[off] = v;
        } else if (epi == 1) {
          ((unsigned short*)Cout)[off] = f2b(v);
        } else if (epi == 2) {
          float x = v + bias[gn];
          float u = 0.7978845608028654f * (x + 0.044715f * x * x * x);
          ((unsigned short*)Cout)[off] = f2b(0.5f * x * (1.f + tanhf(u)));
        } else if (epi == 3) {
          ((float*)Cout)[off] = v + res[off];
        } else if (epi == 4) {
          ((float*)Cout)[off] = v + bias[gn] + res[off];
        } else if (epi == 5) {
          float x = v + bias[gn];
          ((float*)Cout)[off] = (x > 20.f) ? x : log1pf(__expf(x));
        } else {
          pdst[off] = v;
        }
      }
    }
  }
}

// reduce 4 split-K partials (+bias +res) -> out fp32.  N must be 1024 (=DM).
__global__ __launch_bounds__(256) void reduce4_k(const float* __restrict__ p0,
                                                 const float* __restrict__ p1,
                                                 float* __restrict__ out,
                                                 const float* __restrict__ bias,
                                                 const float* __restrict__ res) {
  int i = blockIdx.x * 256 + threadIdx.x;  // < T_TOK*DM
  const size_t TN = (size_t)T_TOK * DM;
  float s = p0[i] + p0[i + TN] + p1[i] + p1[i + TN];
  if (bias) s += bias[i & (DM - 1)];
  if (res) s += res[i];
  out[i] = s;
}

// ---------------------------------------------------------------------------
// x_proj split-K bf16 MFMA: part[ks][m][n] = sum_{k chunk} xcb[m,k]*W[n,k]
// ---------------------------------------------------------------------------
__global__ __launch_bounds__(256) void xproj_k(
    const unsigned short* __restrict__ xcb, const unsigned short* __restrict__ wpb,
    float* __restrict__ part) {
  __shared__ __align__(16) unsigned short As[4][64][8];
  __shared__ __align__(16) unsigned short Bs[32][96][8];
  int tid = threadIdx.x;
  int lane = tid & 63, wv = tid >> 6;
  int ml = lane & 15, kq = lane >> 4;
  int m0 = blockIdx.x * 64;
  int ks = blockIdx.y;
  int kbase = ks * 256;
  for (int e = tid; e < 3072; e += 256) {
    int row = e >> 5, slab = e & 31;
    *(int4*)&Bs[slab][row][0] = *(const int4*)(wpb + (size_t)row * DI + kbase + slab * 8);
  }
  floatx4 acc[6] = {};
  for (int s = 0; s < 8; ++s) {
    async16(&As[wv][0][0],
            xcb + (size_t)(m0 + lane) * DI + kbase + s * 32 + wv * 8);
    __syncthreads();
    short8 af = *(const short8*)&As[kq][wv * 16 + ml][0];
#pragma unroll
    for (int j = 0; j < 6; ++j) {
      short8 bf = *(const short8*)&Bs[s * 4 + kq][j * 16 + ml][0];
      acc[j] = __builtin_amdgcn_mfma_f32_16x16x32_bf16(af, bf, acc[j], 0, 0, 0);
    }
    __syncthreads();
  }
  float* dst = part + (size_t)ks * (T_TOK * XD);
#pragma unroll
  for (int j = 0; j < 6; ++j) {
    int gn = j * 16 + ml;
    int gm = m0 + wv * 16 + kq * 4;
#pragma unroll
    for (int r = 0; r < 4; ++r) dst[(size_t)(gm + r) * XD + gn] = acc[j][r];
  }
}

// reduce x_proj partials -> x_dbl fp32 [T,96]; dt part as bf16 [T,64]
__global__ __launch_bounds__(256) void xreduce_k(const float* __restrict__ part,
                                                 float* __restrict__ xdbl,
                                                 unsigned short* __restrict__ dtb) {
  int i = blockIdx.x * 256 + threadIdx.x;  // < T_TOK*XD
  float s = 0.f;
#pragma unroll
  for (int ks = 0; ks < SPLITK; ++ks) s += part[(size_t)ks * (T_TOK * XD) + i];
  xdbl[i] = s;
  int t = i / XD, c = i - t * XD;
  if (c < DTR) dtb[(size_t)t * DTR + c] = f2b(s);
}

// ---------------------------------------------------------------------------
// Causal depthwise conv (k=4) + bias + SiLU. Reads bf16 x-half of xz
// (row stride 2*DI). Emits fp32 (scan) + bf16 (x_proj).
// ---------------------------------------------------------------------------
__global__ __launch_bounds__(256) void conv_silu_k(
    const unsigned short* __restrict__ xzb, const float* __restrict__ cw,
    const float* __restrict__ cb, float* __restrict__ xc,
    unsigned short* __restrict__ xcb) {
  int idx = blockIdx.x * 256 + threadIdx.x;  // over T_TOK*DI
  int d = idx & (DI - 1);
  int t = idx >> 11;
  int l = t & (SEQ - 1);
  const unsigned short* base = xzb + (size_t)t * (2 * DI) + d;
  float4 w4 = *(const float4*)(cw + d * 4);
  float s = cb[d] + w4.w * b2f(base[0]);
  if (l >= 1) s = fmaf(w4.z, b2f(base[-(2 * DI)]), s);
  if (l >= 2) s = fmaf(w4.y, b2f(base[-2 * (2 * DI)]), s);
  if (l >= 3) s = fmaf(w4.x, b2f(base[-3 * (2 * DI)]), s);
  float y = s / (1.f + __expf(-s));  // silu
  xc[(size_t)t * DI + d] = y;
  xcb[(size_t)t * DI + d] = f2b(y);
}

// ---------------------------------------------------------------------------
// Chunked selective scan, 4 states per thread.
// idx: [1:0]=ng (state group), [12:2]=d, [16:13]=chunk, [17]=b
// Pass 1: per-chunk (prod dA, local h_end) for 4 states; float4 stores.
// Summary layout: [b][c][d][n], n innermost.
// ---------------------------------------------------------------------------
__global__ __launch_bounds__(256) void scan1_k(
    const float* __restrict__ delta, const float* __restrict__ xc,
    const float* __restrict__ xdbl, const float* __restrict__ A_log,
    float* __restrict__ hend, float* __restrict__ aprod) {
  int idx = blockIdx.x * 256 + threadIdx.x;
  int ng = idx & 3;
  int d = (idx >> 2) & (DI - 1);
  int c = (idx >> 13) & (NCHK - 1);
  int b = idx >> 17;
  const float* ap_ = A_log + d * NST + ng * 4;
  float a0 = -__expf(ap_[0]), a1 = -__expf(ap_[1]);
  float a2 = -__expf(ap_[2]), a3 = -__expf(ap_[3]);
  float h0 = 0.f, h1 = 0.f, h2 = 0.f, h3 = 0.f;
  float q0 = 1.f, q1 = 1.f, q2 = 1.f, q3 = 1.f;
  int t = b * SEQ + c * CHK;
  const float* dp = delta + (size_t)t * DI + d;
  const float* xp = xc + (size_t)t * DI + d;
  const float* bp = xdbl + (size_t)t * XD + DTR + ng * 4;
  for (int l = 0; l < CHK; ++l) {
    float dv = *dp;
    float xv = *xp;
    float4 B4 = *(const float4*)bp;
    float dx = dv * xv;
    float e0 = __expf(dv * a0), e1 = __expf(dv * a1);
    float e2 = __expf(dv * a2), e3 = __expf(dv * a3);
    q0 *= e0; q1 *= e1; q2 *= e2; q3 *= e3;
    h0 = fmaf(e0, h0, dx * B4.x);
    h1 = fmaf(e1, h1, dx * B4.y);
    h2 = fmaf(e2, h2, dx * B4.z);
    h3 = fmaf(e3, h3, dx * B4.w);
    dp += DI; xp += DI; bp += XD;
  }
  size_t o = ((size_t)(b * NCHK + c) * DI + d) * NST + ng * 4;
  *(float4*)&hend[o] = make_float4(h0, h1, h2, h3);
  *(float4*)&aprod[o] = make_float4(q0, q1, q2, q3);
}

// Pass 2: compose prior summaries, replay chunk, 4-lane reduce, gate, bf16 y.
__global__ __launch_bounds__(256) void scan2_k(
    const float* __restrict__ delta, const float* __restrict__ xc,
    const float* __restrict__ xdbl, const unsigned short* __restrict__ xzb,
    const float* __restrict__ A_log, const float* __restrict__ Dsk,
    const float* __restrict__ hend, const float* __restrict__ aprod,
    unsigned short* __restrict__ y) {
  int idx = blockIdx.x * 256 + threadIdx.x;
  int ng = idx & 3;
  int d = (idx >> 2) & (DI - 1);
  int c = (idx >> 13) & (NCHK - 1);
  int b = idx >> 17;
  const float* ap_ = A_log + d * NST + ng * 4;
  float a0 = -__expf(ap_[0]), a1 = -__expf(ap_[1]);
  float a2 = -__expf(ap_[2]), a3 = -__expf(ap_[3]);
  float dskip = Dsk[d];
  float h0 = 0.f, h1 = 0.f, h2 = 0.f, h3 = 0.f;
  for (int pc = 0; pc < c; ++pc) {
    size_t o = ((size_t)(b * NCHK + pc) * DI + d) * NST + ng * 4;
    float4 ap4 = *(const float4*)&aprod[o];
    float4 he4 = *(const float4*)&hend[o];
    h0 = fmaf(ap4.x, h0, he4.x);
    h1 = fmaf(ap4.y, h1, he4.y);
    h2 = fmaf(ap4.z, h2, he4.z);
    h3 = fmaf(ap4.w, h3, he4.w);
  }
  int t = b * SEQ + c * CHK;
  const float* dp = delta + (size_t)t * DI + d;
  const float* xp = xc + (size_t)t * DI + d;
  const float* bp = xdbl + (size_t)t * XD + DTR + ng * 4;
  const float* cp = xdbl + (size_t)t * XD + DTR + NST + ng * 4;
  const unsigned short* zp = xzb + (size_t)t * (2 * DI) + DI + d;
  unsigned short* yp = y + (size_t)t * DI + d;
  for (int l = 0; l < CHK; ++l) {
    float dv = *dp;
    float xv = *xp;
    float4 B4 = *(const float4*)bp;
    float4 C4 = *(const float4*)cp;
    float dx = dv * xv;
    float e0 = __expf(dv * a0), e1 = __expf(dv * a1);
    float e2 = __expf(dv * a2), e3 = __expf(dv * a3);
    h0 = fmaf(e0, h0, dx * B4.x);
    h1 = fmaf(e1, h1, dx * B4.y);
    h2 = fmaf(e2, h2, dx * B4.z);
    h3 = fmaf(e3, h3, dx * B4.w);
    float contrib = h0 * C4.x + h1 * C4.y + h2 * C4.z + h3 * C4.w;
    contrib += __shfl_xor(contrib, 1);
    contrib += __shfl_xor(contrib, 2);
    if (ng == 0) {
      float zv = b2f(*zp);
      float sig = zv / (1.f + __expf(-zv));
      *yp = f2b((contrib + xv * dskip) * sig);
    }
    dp += DI; xp += DI; bp += XD; cp += XD; zp += 2 * DI; yp += DI;
  }
}

// ---------------------------------------------------------------------------
extern "C" void kernel_launch(void* const* d_in, const int* in_sizes, int n_in,
                              void* d_out, int out_size, void* d_ws,
                              size_t ws_size, hipStream_t stream) {
  const float* x_in      = (const float*)d_in[0];
  const float* ln0_w     = (const float*)d_in[1];
  const float* ln0_b     = (const float*)d_in[2];
  const float* ln1_w     = (const float*)d_in[3];
  const float* ln1_b     = (const float*)d_in[4];
  const float* ln2_w     = (const float*)d_in[5];
  const float* ln2_b     = (const float*)d_in[6];
  const float* in_proj_w = (const float*)d_in[7];
  const float* conv_w    = (const float*)d_in[8];
  const float* conv_b    = (const float*)d_in[9];
  const float* x_proj_w  = (const float*)d_in[10];
  const float* dt_proj_w = (const float*)d_in[11];
  const float* dt_proj_b = (const float*)d_in[12];
  const float* A_log     = (const float*)d_in[13];
  const float* D_skip    = (const float*)d_in[14];
  const float* out_proj_w= (const float*)d_in[15];
  const float* ffn_w1    = (const float*)d_in[16];
  const float* ffn_b1    = (const float*)d_in[17];
  const float* ffn_w2    = (const float*)d_in[18];
  const float* ffn_b2    = (const float*)d_in[19];
  float* out = (float*)d_out;

  // Workspace layout (floats), liveness-aliased; total 20.12M floats = 80.5 MB
  float* ws    = (float*)d_ws;
  float* xws   = ws;                     // [T,DM] fp32 residual          2.097M
  float* big   = xws + 2097152;          // xzb bf16 [T,4096] / hbf bf16  4.194M
  float* r2    = big + 4194304;          // ybf bf16 [T,DI]               2.097M
  float* xcws  = r2 + 2097152;           // xc fp32 / split-K partials    4.194M
  float* xdbl  = xcws + 4194304;         // [T,96] fp32                   0.197M
  float* dws   = xdbl + 196608;          // xcb bf16 / delta fp32 / parts 4.194M
  float* ubf_f = dws + 4194304;          // [T,DM] bf16 LN out            1.049M
  float* wbf_f = ubf_f + 1048576;        // staging region                2.097M
  // aliases (timeline-checked):
  unsigned short* xzb  = (unsigned short*)big;   // in_proj out, dies after scan2
  unsigned short* hbf  = (unsigned short*)big;   // ffn1 -> ffn2 [T,FFN] bf16
  unsigned short* ybf  = (unsigned short*)r2;    // scan2 -> out_proj
  unsigned short* ubf  = (unsigned short*)ubf_f;
  unsigned short* xcb  = (unsigned short*)dws;   // conv bf16, dies before dt_proj
  unsigned short* wbf  = (unsigned short*)wbf_f;
  float* part  = wbf_f;                          // xproj partials [8][T,96] 1.573M
  unsigned short* wpb = (unsigned short*)(wbf_f + 1572864);  // x_proj_w bf16
  unsigned short* dtb = (unsigned short*)(wbf_f + 1671168);  // dt bf16 [T,64]
  unsigned short* dwb = (unsigned short*)(wbf_f + 1736704);  // dt_proj_w bf16
  // scan summaries overwrite the whole staging region after dt_proj:
  float* hend  = wbf_f;                  // [1048576] = B*NCHK*DI*NST
  float* aprod = wbf_f + 1048576;        // [1048576]

  // 1: convert in_proj_w -> bf16 (4096x1024)
  f2b_k<<<(4096 * 1024) / 1024, 256, 0, stream>>>(in_proj_w, wbf);
  // 2-3: LN0 (fp32), LN1 (bf16)
  ln_k<<<T_TOK, 256, 0, stream>>>(x_in, ln0_w, ln0_b, xws);
  ln_bf_k<<<T_TOK, 256, 0, stream>>>(xws, ln1_w, ln1_b, ubf);
  // 4: in_proj, single dispatch N=4096 -> xzb bf16 (512 blocks)
  {
    dim3 g((2 * DI) / 128, T_TOK / 128, 1);
    gemm_bf16<<<g, 256, 0, stream>>>(ubf, DM, wbf, DM, xzb, 2 * DI, DM, 1,
                                     nullptr, nullptr, nullptr, nullptr);
  }
  // 5: causal conv + silu (bf16 in) -> xc fp32 + xcb bf16
  conv_silu_k<<<(T_TOK * DI) / 256, 256, 0, stream>>>(xzb, conv_w, conv_b, xcws, xcb);
  // 6: x_proj / dt_proj weights -> bf16
  f2b_k<<<(XD * DI) / 1024, 256, 0, stream>>>(x_proj_w, wpb);
  f2b_k<<<(DI * DTR) / 1024, 256, 0, stream>>>(dt_proj_w, dwb);
  // 7: x_proj split-K MFMA + reduce -> xdbl fp32, dtb bf16
  {
    dim3 g(T_TOK / 64, SPLITK);
    xproj_k<<<g, 256, 0, stream>>>(xcb, wpb, part);
    xreduce_k<<<(T_TOK * XD) / 256, 256, 0, stream>>>(part, xdbl, dtb);
  }
  // 8: dt_proj + softplus (bf16 MFMA) -> delta fp32
  {
    dim3 g(DI / 128, T_TOK / 128, 1);
    gemm_bf16<<<g, 256, 0, stream>>>(dtb, DTR, dwb, DTR, dws, DI, DTR, 5,
                                     dt_proj_b, nullptr, nullptr, nullptr);
  }
  // 9-10: chunked scan, 4 states/thread (summaries alias dead staging region)
  {
    int nthreads = 2 * NCHK * DI * 4;  // b * chunks * d * state-groups = 262144
    scan1_k<<<nthreads / 256, 256, 0, stream>>>(dws, xcws, xdbl, A_log,
                                                hend, aprod);
    scan2_k<<<nthreads / 256, 256, 0, stream>>>(dws, xcws, xdbl, xzb,
                                                A_log, D_skip, hend, aprod, ybf);
  }
  // 11: out_proj split-K x4 (512 blocks) + reduce(+res) -> xws
  f2b_k<<<(DM * DI) / 1024, 256, 0, stream>>>(out_proj_w, wbf);
  {
    dim3 g(DM / 128, T_TOK / 128, 4);
    gemm_bf16<<<g, 256, 0, stream>>>(ybf, DI, wbf, DI, nullptr, DM, DI / 4, 6,
                                     nullptr, nullptr, xcws, dws);
    reduce4_k<<<(T_TOK * DM) / 256, 256, 0, stream>>>(xcws, dws, xws, nullptr, xws);
  }
  // 12: LN2 -> bf16
  ln_bf_k<<<T_TOK, 256, 0, stream>>>(xws, ln2_w, ln2_b, ubf);
  // 13: ffn1 + bias + gelu -> hbf bf16 (512 blocks)
  f2b_k<<<(FFN * DM) / 1024, 256, 0, stream>>>(ffn_w1, wbf);
  {
    dim3 g(FFN / 128, T_TOK / 128, 1);
    gemm_bf16<<<g, 256, 0, stream>>>(ubf, DM, wbf, DM, hbf, FFN, DM, 2,
                                     ffn_b1, nullptr, nullptr, nullptr);
  }
  // 14: ffn2 split-K x4 (512 blocks) + reduce(+bias+res) -> d_out
  f2b_k<<<(DM * FFN) / 1024, 256, 0, stream>>>(ffn_w2, wbf);
  {
    dim3 g(DM / 128, T_TOK / 128, 4);
    gemm_bf16<<<g, 256, 0, stream>>>(hbf, FFN, wbf, FFN, nullptr, DM, FFN / 4, 6,
                                     nullptr, nullptr, dws, xcws);
    reduce4_k<<<(T_TOK * DM) / 256, 256, 0, stream>>>(dws, xcws, out, ffn_b2, xws);
  }
}

// Round 7
// 553.622 us; speedup vs baseline: 3.8749x; 1.0225x over previous
//
#include <hip/hip_runtime.h>
#include <math.h>

// Problem constants (match reference)
#define T_TOK 2048   // B*L
#define SEQ   1024   // L
#define DM    1024   // d_model
#define DI    2048   // d_inner
#define FFN   4096
#define NST   16     // d_state
#define DTR   64     // dt_rank
#define XD    96     // dt_rank + 2*d_state
#define CHK   64     // scan chunk length
#define NCHK  16     // chunks per sequence
#define SPLITK 8     // x_proj K-splits (K chunk = 256)

typedef __attribute__((ext_vector_type(8))) short short8;
typedef __attribute__((ext_vector_type(4))) float floatx4;

__device__ __forceinline__ unsigned short f2b(float f) {
  unsigned u = __float_as_uint(f);
  unsigned r = (u + 0x7fff + ((u >> 16) & 1)) >> 16;  // RNE
  return (unsigned short)r;
}
__device__ __forceinline__ float b2f(unsigned short s) {
  return __uint_as_float(((unsigned)s) << 16);
}

// async global->LDS, 16 B per lane. lds must be the wave-uniform base
// (lane 0's destination); HW adds lane*16.
typedef const __attribute__((address_space(1))) unsigned int g_uint;
typedef __attribute__((address_space(3))) unsigned int l_uint;
__device__ __forceinline__ void async16(void* lds, const void* g) {
  __builtin_amdgcn_global_load_lds((g_uint*)(size_t)g,
                                   (l_uint*)(unsigned)(size_t)lds, 16, 0, 0);
}

// ---------------------------------------------------------------------------
// fp32 -> bf16 bulk convert (n multiple of 1024); 4 elems/thread
// ---------------------------------------------------------------------------
__global__ __launch_bounds__(256) void f2b_k(const float* __restrict__ in,
                                             unsigned short* __restrict__ out) {
  int i = blockIdx.x * 256 + threadIdx.x;
  float4 v = ((const float4*)in)[i];
  ushort4 o;
  o.x = f2b(v.x); o.y = f2b(v.y); o.z = f2b(v.z); o.w = f2b(v.w);
  ((ushort4*)out)[i] = o;
}

// ---------------------------------------------------------------------------
// LayerNorm fp32 out: one block per token, 256 threads x 4 elems = 1024 dims
// ---------------------------------------------------------------------------
__global__ __launch_bounds__(256) void ln_k(const float* __restrict__ in,
                                            const float* __restrict__ w,
                                            const float* __restrict__ bb,
                                            float* __restrict__ out) {
  int t = blockIdx.x;
  int tid = threadIdx.x;
  const float* row = in + (size_t)t * DM;
  float4 v = *(const float4*)(row + tid * 4);
  float s = v.x + v.y + v.z + v.w;
  __shared__ float sm[2][4];
  for (int off = 32; off > 0; off >>= 1) s += __shfl_down(s, off, 64);
  int wv = tid >> 6, ln = tid & 63;
  if (ln == 0) sm[0][wv] = s;
  __syncthreads();
  float mu = (sm[0][0] + sm[0][1] + sm[0][2] + sm[0][3]) * (1.0f / DM);
  float d0 = v.x - mu, d1 = v.y - mu, d2 = v.z - mu, d3 = v.w - mu;
  float sq = d0 * d0 + d1 * d1 + d2 * d2 + d3 * d3;
  for (int off = 32; off > 0; off >>= 1) sq += __shfl_down(sq, off, 64);
  if (ln == 0) sm[1][wv] = sq;
  __syncthreads();
  float var = (sm[1][0] + sm[1][1] + sm[1][2] + sm[1][3]) * (1.0f / DM);
  float rs = rsqrtf(var + 1e-5f);
  float4 w4 = *(const float4*)(w + tid * 4);
  float4 b4 = *(const float4*)(bb + tid * 4);
  float4 o;
  o.x = d0 * rs * w4.x + b4.x;
  o.y = d1 * rs * w4.y + b4.y;
  o.z = d2 * rs * w4.z + b4.z;
  o.w = d3 * rs * w4.w + b4.w;
  *(float4*)(out + (size_t)t * DM + tid * 4) = o;
}

// LayerNorm bf16 out
__global__ __launch_bounds__(256) void ln_bf_k(const float* __restrict__ in,
                                               const float* __restrict__ w,
                                               const float* __restrict__ bb,
                                               unsigned short* __restrict__ out) {
  int t = blockIdx.x;
  int tid = threadIdx.x;
  const float* row = in + (size_t)t * DM;
  float4 v = *(const float4*)(row + tid * 4);
  float s = v.x + v.y + v.z + v.w;
  __shared__ float sm[2][4];
  for (int off = 32; off > 0; off >>= 1) s += __shfl_down(s, off, 64);
  int wv = tid >> 6, ln = tid & 63;
  if (ln == 0) sm[0][wv] = s;
  __syncthreads();
  float mu = (sm[0][0] + sm[0][1] + sm[0][2] + sm[0][3]) * (1.0f / DM);
  float d0 = v.x - mu, d1 = v.y - mu, d2 = v.z - mu, d3 = v.w - mu;
  float sq = d0 * d0 + d1 * d1 + d2 * d2 + d3 * d3;
  for (int off = 32; off > 0; off >>= 1) sq += __shfl_down(sq, off, 64);
  if (ln == 0) sm[1][wv] = sq;
  __syncthreads();
  float var = (sm[1][0] + sm[1][1] + sm[1][2] + sm[1][3]) * (1.0f / DM);
  float rs = rsqrtf(var + 1e-5f);
  float4 w4 = *(const float4*)(w + tid * 4);
  float4 b4 = *(const float4*)(bb + tid * 4);
  ushort4 o;
  o.x = f2b(d0 * rs * w4.x + b4.x);
  o.y = f2b(d1 * rs * w4.y + b4.y);
  o.z = f2b(d2 * rs * w4.z + b4.z);
  o.w = f2b(d3 * rs * w4.w + b4.w);
  *(ushort4*)(out + (size_t)t * DM + tid * 4) = o;
}

// ---------------------------------------------------------------------------
// bf16 MFMA GEMM (NT): C[m,n] = sum_k A[m,k]*W[n,k].  128x128 tile, 4 waves
// (2x2), 16x16x32 MFMA, double-buffered global_load_lds staging: prefetch
// tile k+1 into the alternate LDS buffer right after the barrier, compute
// tile k; one barrier per iteration (its vmcnt(0) drain finds a load that
// has been in flight for a full compute iteration).  Split-K via blockIdx.z.
// epi: 0 fp32 | 1 bf16 | 2 gelu(acc+bias) bf16 | 3 acc+res fp32
//      4 acc+bias+res fp32 | 5 softplus(acc+bias) fp32 | 6 split-K fp32 partial
// partial base: z in {0,1} -> p0 + z*T*ldc ; z in {2,3} -> p1 + (z-2)*T*ldc
// ---------------------------------------------------------------------------
__global__ __launch_bounds__(256) void gemm_bf16(
    const unsigned short* __restrict__ A, int lda,
    const unsigned short* __restrict__ Bw, int ldb,
    void* __restrict__ Cout, int ldc, int Kc, int epi,
    const float* __restrict__ bias, const float* __restrict__ res,
    float* __restrict__ p0, float* __restrict__ p1) {
  __shared__ __align__(16) unsigned short As[2][4][128][8];  // [buf][slab][row][8k]
  __shared__ __align__(16) unsigned short Bs[2][4][128][8];
  int tid = threadIdx.x;
  int lane = tid & 63, wv = tid >> 6;
  int wr = wv >> 1, wc = wv & 1;
  int m0 = blockIdx.y * 128, n0 = blockIdx.x * 128;
  int ml = lane & 15, kq = lane >> 4;
  int kstart = blockIdx.z * Kc;
  int niter = Kc / 32;
  // per-thread staging indices (same pattern as the proven single-buffer ver)
  int c0 = tid, c1 = tid + 256;
  int row_a = c0 & 127, slab_a = c0 >> 7;
  int row_b = c1 & 127, slab_b = c1 >> 7;
  int cw0 = wv * 64, cw1 = wv * 64 + 256;
  int row0a = cw0 & 127, slab0a = cw0 >> 7;
  int row0b = cw1 & 127, slab0b = cw1 >> 7;
  // prologue: stage tile 0 into buf 0
  {
    int k0 = kstart;
    async16(&As[0][slab0a][row0a][0], A + (size_t)(m0 + row_a) * lda + k0 + slab_a * 8);
    async16(&Bs[0][slab0a][row0a][0], Bw + (size_t)(n0 + row_a) * ldb + k0 + slab_a * 8);
    async16(&As[0][slab0b][row0b][0], A + (size_t)(m0 + row_b) * lda + k0 + slab_b * 8);
    async16(&Bs[0][slab0b][row0b][0], Bw + (size_t)(n0 + row_b) * ldb + k0 + slab_b * 8);
  }
  floatx4 acc[4][4] = {};
  for (int it = 0; it < niter; ++it) {
    __syncthreads();  // buf(it&1) staged; prev iter's LDS reads done
    int cur = it & 1;
    if (it + 1 < niter) {
      int k0 = kstart + (it + 1) * 32;
      int nb = cur ^ 1;
      async16(&As[nb][slab0a][row0a][0], A + (size_t)(m0 + row_a) * lda + k0 + slab_a * 8);
      async16(&Bs[nb][slab0a][row0a][0], Bw + (size_t)(n0 + row_a) * ldb + k0 + slab_a * 8);
      async16(&As[nb][slab0b][row0b][0], A + (size_t)(m0 + row_b) * lda + k0 + slab_b * 8);
      async16(&Bs[nb][slab0b][row0b][0], Bw + (size_t)(n0 + row_b) * ldb + k0 + slab_b * 8);
    }
    short8 af[4], bfr[4];
#pragma unroll
    for (int i = 0; i < 4; ++i)
      af[i] = *(const short8*)&As[cur][kq][wr * 64 + i * 16 + ml][0];
#pragma unroll
    for (int j = 0; j < 4; ++j)
      bfr[j] = *(const short8*)&Bs[cur][kq][wc * 64 + j * 16 + ml][0];
#pragma unroll
    for (int i = 0; i < 4; ++i)
#pragma unroll
      for (int j = 0; j < 4; ++j)
        acc[i][j] =
            __builtin_amdgcn_mfma_f32_16x16x32_bf16(af[i], bfr[j], acc[i][j], 0, 0, 0);
  }
  float* pdst = nullptr;
  if (epi == 6) {
    pdst = (blockIdx.z & 2) ? p1 : p0;
    pdst += (size_t)(blockIdx.z & 1) * T_TOK * ldc;
  }
  // epilogue: D row = (lane>>4)*4 + r, col = lane&15
#pragma unroll
  for (int i = 0; i < 4; ++i) {
    int gm = m0 + wr * 64 + i * 16 + kq * 4;
#pragma unroll
    for (int j = 0; j < 4; ++j) {
      int gn = n0 + wc * 64 + j * 16 + ml;
#pragma unroll
      for (int r = 0; r < 4; ++r) {
        float v = acc[i][j][r];
        size_t off = (size_t)(gm + r) * ldc + gn;
        if (epi == 0) {
          ((float*)Cout)[off] = v;
        } else if (epi == 1) {
          ((unsigned short*)Cout)[off] = f2b(v);
        } else if (epi == 2) {
          float x = v + bias[gn];
          float u = 0.7978845608028654f * (x + 0.044715f * x * x * x);
          ((unsigned short*)Cout)[off] = f2b(0.5f * x * (1.f + tanhf(u)));
        } else if (epi == 3) {
          ((float*)Cout)[off] = v + res[off];
        } else if (epi == 4) {
          ((float*)Cout)[off] = v + bias[gn] + res[off];
        } else if (epi == 5) {
          float x = v + bias[gn];
          ((float*)Cout)[off] = (x > 20.f) ? x : log1pf(__expf(x));
        } else {
          pdst[off] = v;
        }
      }
    }
  }
}

// reduce 4 split-K partials (+bias +res) -> out fp32.  N must be 1024 (=DM).
__global__ __launch_bounds__(256) void reduce4_k(const float* __restrict__ p0,
                                                 const float* __restrict__ p1,
                                                 float* __restrict__ out,
                                                 const float* __restrict__ bias,
                                                 const float* __restrict__ res) {
  int i = blockIdx.x * 256 + threadIdx.x;  // < T_TOK*DM
  const size_t TN = (size_t)T_TOK * DM;
  float s = p0[i] + p0[i + TN] + p1[i] + p1[i + TN];
  if (bias) s += bias[i & (DM - 1)];
  if (res) s += res[i];
  out[i] = s;
}

// ---------------------------------------------------------------------------
// x_proj split-K bf16 MFMA: part[ks][m][n] = sum_{k chunk} xcb[m,k]*W[n,k]
// ---------------------------------------------------------------------------
__global__ __launch_bounds__(256) void xproj_k(
    const unsigned short* __restrict__ xcb, const unsigned short* __restrict__ wpb,
    float* __restrict__ part) {
  __shared__ __align__(16) unsigned short As[4][64][8];
  __shared__ __align__(16) unsigned short Bs[32][96][8];
  int tid = threadIdx.x;
  int lane = tid & 63, wv = tid >> 6;
  int ml = lane & 15, kq = lane >> 4;
  int m0 = blockIdx.x * 64;
  int ks = blockIdx.y;
  int kbase = ks * 256;
  for (int e = tid; e < 3072; e += 256) {
    int row = e >> 5, slab = e & 31;
    *(int4*)&Bs[slab][row][0] = *(const int4*)(wpb + (size_t)row * DI + kbase + slab * 8);
  }
  floatx4 acc[6] = {};
  for (int s = 0; s < 8; ++s) {
    async16(&As[wv][0][0],
            xcb + (size_t)(m0 + lane) * DI + kbase + s * 32 + wv * 8);
    __syncthreads();
    short8 af = *(const short8*)&As[kq][wv * 16 + ml][0];
#pragma unroll
    for (int j = 0; j < 6; ++j) {
      short8 bf = *(const short8*)&Bs[s * 4 + kq][j * 16 + ml][0];
      acc[j] = __builtin_amdgcn_mfma_f32_16x16x32_bf16(af, bf, acc[j], 0, 0, 0);
    }
    __syncthreads();
  }
  float* dst = part + (size_t)ks * (T_TOK * XD);
#pragma unroll
  for (int j = 0; j < 6; ++j) {
    int gn = j * 16 + ml;
    int gm = m0 + wv * 16 + kq * 4;
#pragma unroll
    for (int r = 0; r < 4; ++r) dst[(size_t)(gm + r) * XD + gn] = acc[j][r];
  }
}

// reduce x_proj partials -> x_dbl fp32 [T,96]; dt part as bf16 [T,64]
__global__ __launch_bounds__(256) void xreduce_k(const float* __restrict__ part,
                                                 float* __restrict__ xdbl,
                                                 unsigned short* __restrict__ dtb) {
  int i = blockIdx.x * 256 + threadIdx.x;  // < T_TOK*XD
  float s = 0.f;
#pragma unroll
  for (int ks = 0; ks < SPLITK; ++ks) s += part[(size_t)ks * (T_TOK * XD) + i];
  xdbl[i] = s;
  int t = i / XD, c = i - t * XD;
  if (c < DTR) dtb[(size_t)t * DTR + c] = f2b(s);
}

// ---------------------------------------------------------------------------
// Causal depthwise conv (k=4) + bias + SiLU. Reads bf16 x-half of xz
// (row stride 2*DI). Emits fp32 (scan) + bf16 (x_proj).
// ---------------------------------------------------------------------------
__global__ __launch_bounds__(256) void conv_silu_k(
    const unsigned short* __restrict__ xzb, const float* __restrict__ cw,
    const float* __restrict__ cb, float* __restrict__ xc,
    unsigned short* __restrict__ xcb) {
  int idx = blockIdx.x * 256 + threadIdx.x;  // over T_TOK*DI
  int d = idx & (DI - 1);
  int t = idx >> 11;
  int l = t & (SEQ - 1);
  const unsigned short* base = xzb + (size_t)t * (2 * DI) + d;
  float4 w4 = *(const float4*)(cw + d * 4);
  float s = cb[d] + w4.w * b2f(base[0]);
  if (l >= 1) s = fmaf(w4.z, b2f(base[-(2 * DI)]), s);
  if (l >= 2) s = fmaf(w4.y, b2f(base[-2 * (2 * DI)]), s);
  if (l >= 3) s = fmaf(w4.x, b2f(base[-3 * (2 * DI)]), s);
  float y = s / (1.f + __expf(-s));  // silu
  xc[(size_t)t * DI + d] = y;
  xcb[(size_t)t * DI + d] = f2b(y);
}

// ---------------------------------------------------------------------------
// Chunked selective scan, 4 states per thread.
// idx: [1:0]=ng (state group), [12:2]=d, [16:13]=chunk, [17]=b
// Pass 1: per-chunk (prod dA, local h_end) for 4 states; float4 stores.
// Summary layout: [b][c][d][n], n innermost.
// ---------------------------------------------------------------------------
__global__ __launch_bounds__(256) void scan1_k(
    const float* __restrict__ delta, const float* __restrict__ xc,
    const float* __restrict__ xdbl, const float* __restrict__ A_log,
    float* __restrict__ hend, float* __restrict__ aprod) {
  int idx = blockIdx.x * 256 + threadIdx.x;
  int ng = idx & 3;
  int d = (idx >> 2) & (DI - 1);
  int c = (idx >> 13) & (NCHK - 1);
  int b = idx >> 17;
  const float* ap_ = A_log + d * NST + ng * 4;
  float a0 = -__expf(ap_[0]), a1 = -__expf(ap_[1]);
  float a2 = -__expf(ap_[2]), a3 = -__expf(ap_[3]);
  float h0 = 0.f, h1 = 0.f, h2 = 0.f, h3 = 0.f;
  float q0 = 1.f, q1 = 1.f, q2 = 1.f, q3 = 1.f;
  int t = b * SEQ + c * CHK;
  const float* dp = delta + (size_t)t * DI + d;
  const float* xp = xc + (size_t)t * DI + d;
  const float* bp = xdbl + (size_t)t * XD + DTR + ng * 4;
  for (int l = 0; l < CHK; ++l) {
    float dv = *dp;
    float xv = *xp;
    float4 B4 = *(const float4*)bp;
    float dx = dv * xv;
    float e0 = __expf(dv * a0), e1 = __expf(dv * a1);
    float e2 = __expf(dv * a2), e3 = __expf(dv * a3);
    q0 *= e0; q1 *= e1; q2 *= e2; q3 *= e3;
    h0 = fmaf(e0, h0, dx * B4.x);
    h1 = fmaf(e1, h1, dx * B4.y);
    h2 = fmaf(e2, h2, dx * B4.z);
    h3 = fmaf(e3, h3, dx * B4.w);
    dp += DI; xp += DI; bp += XD;
  }
  size_t o = ((size_t)(b * NCHK + c) * DI + d) * NST + ng * 4;
  *(float4*)&hend[o] = make_float4(h0, h1, h2, h3);
  *(float4*)&aprod[o] = make_float4(q0, q1, q2, q3);
}

// Pass 2: compose prior summaries, replay chunk, 4-lane reduce, gate, bf16 y.
__global__ __launch_bounds__(256) void scan2_k(
    const float* __restrict__ delta, const float* __restrict__ xc,
    const float* __restrict__ xdbl, const unsigned short* __restrict__ xzb,
    const float* __restrict__ A_log, const float* __restrict__ Dsk,
    const float* __restrict__ hend, const float* __restrict__ aprod,
    unsigned short* __restrict__ y) {
  int idx = blockIdx.x * 256 + threadIdx.x;
  int ng = idx & 3;
  int d = (idx >> 2) & (DI - 1);
  int c = (idx >> 13) & (NCHK - 1);
  int b = idx >> 17;
  const float* ap_ = A_log + d * NST + ng * 4;
  float a0 = -__expf(ap_[0]), a1 = -__expf(ap_[1]);
  float a2 = -__expf(ap_[2]), a3 = -__expf(ap_[3]);
  float dskip = Dsk[d];
  float h0 = 0.f, h1 = 0.f, h2 = 0.f, h3 = 0.f;
  for (int pc = 0; pc < c; ++pc) {
    size_t o = ((size_t)(b * NCHK + pc) * DI + d) * NST + ng * 4;
    float4 ap4 = *(const float4*)&aprod[o];
    float4 he4 = *(const float4*)&hend[o];
    h0 = fmaf(ap4.x, h0, he4.x);
    h1 = fmaf(ap4.y, h1, he4.y);
    h2 = fmaf(ap4.z, h2, he4.z);
    h3 = fmaf(ap4.w, h3, he4.w);
  }
  int t = b * SEQ + c * CHK;
  const float* dp = delta + (size_t)t * DI + d;
  const float* xp = xc + (size_t)t * DI + d;
  const float* bp = xdbl + (size_t)t * XD + DTR + ng * 4;
  const float* cp = xdbl + (size_t)t * XD + DTR + NST + ng * 4;
  const unsigned short* zp = xzb + (size_t)t * (2 * DI) + DI + d;
  unsigned short* yp = y + (size_t)t * DI + d;
  for (int l = 0; l < CHK; ++l) {
    float dv = *dp;
    float xv = *xp;
    float4 B4 = *(const float4*)bp;
    float4 C4 = *(const float4*)cp;
    float dx = dv * xv;
    float e0 = __expf(dv * a0), e1 = __expf(dv * a1);
    float e2 = __expf(dv * a2), e3 = __expf(dv * a3);
    h0 = fmaf(e0, h0, dx * B4.x);
    h1 = fmaf(e1, h1, dx * B4.y);
    h2 = fmaf(e2, h2, dx * B4.z);
    h3 = fmaf(e3, h3, dx * B4.w);
    float contrib = h0 * C4.x + h1 * C4.y + h2 * C4.z + h3 * C4.w;
    contrib += __shfl_xor(contrib, 1);
    contrib += __shfl_xor(contrib, 2);
    if (ng == 0) {
      float zv = b2f(*zp);
      float sig = zv / (1.f + __expf(-zv));
      *yp = f2b((contrib + xv * dskip) * sig);
    }
    dp += DI; xp += DI; bp += XD; cp += XD; zp += 2 * DI; yp += DI;
  }
}

// ---------------------------------------------------------------------------
extern "C" void kernel_launch(void* const* d_in, const int* in_sizes, int n_in,
                              void* d_out, int out_size, void* d_ws,
                              size_t ws_size, hipStream_t stream) {
  const float* x_in      = (const float*)d_in[0];
  const float* ln0_w     = (const float*)d_in[1];
  const float* ln0_b     = (const float*)d_in[2];
  const float* ln1_w     = (const float*)d_in[3];
  const float* ln1_b     = (const float*)d_in[4];
  const float* ln2_w     = (const float*)d_in[5];
  const float* ln2_b     = (const float*)d_in[6];
  const float* in_proj_w = (const float*)d_in[7];
  const float* conv_w    = (const float*)d_in[8];
  const float* conv_b    = (const float*)d_in[9];
  const float* x_proj_w  = (const float*)d_in[10];
  const float* dt_proj_w = (const float*)d_in[11];
  const float* dt_proj_b = (const float*)d_in[12];
  const float* A_log     = (const float*)d_in[13];
  const float* D_skip    = (const float*)d_in[14];
  const float* out_proj_w= (const float*)d_in[15];
  const float* ffn_w1    = (const float*)d_in[16];
  const float* ffn_b1    = (const float*)d_in[17];
  const float* ffn_w2    = (const float*)d_in[18];
  const float* ffn_b2    = (const float*)d_in[19];
  float* out = (float*)d_out;

  // Workspace layout (floats), liveness-aliased; total 20.12M floats = 80.5 MB
  float* ws    = (float*)d_ws;
  float* xws   = ws;                     // [T,DM] fp32 residual          2.097M
  float* big   = xws + 2097152;          // xzb bf16 [T,4096] / hbf bf16  4.194M
  float* r2    = big + 4194304;          // ybf bf16 [T,DI]               2.097M
  float* xcws  = r2 + 2097152;           // xc fp32 / split-K partials    4.194M
  float* xdbl  = xcws + 4194304;         // [T,96] fp32                   0.197M
  float* dws   = xdbl + 196608;          // xcb bf16 / delta fp32 / parts 4.194M
  float* ubf_f = dws + 4194304;          // [T,DM] bf16 LN out            1.049M
  float* wbf_f = ubf_f + 1048576;        // staging region                2.097M
  // aliases (timeline-checked):
  unsigned short* xzb  = (unsigned short*)big;   // in_proj out, dies after scan2
  unsigned short* hbf  = (unsigned short*)big;   // ffn1 -> ffn2 [T,FFN] bf16
  unsigned short* ybf  = (unsigned short*)r2;    // scan2 -> out_proj
  unsigned short* ubf  = (unsigned short*)ubf_f;
  unsigned short* xcb  = (unsigned short*)dws;   // conv bf16, dies before dt_proj
  unsigned short* wbf  = (unsigned short*)wbf_f;
  float* part  = wbf_f;                          // xproj partials [8][T,96] 1.573M
  unsigned short* wpb = (unsigned short*)(wbf_f + 1572864);  // x_proj_w bf16
  unsigned short* dtb = (unsigned short*)(wbf_f + 1671168);  // dt bf16 [T,64]
  unsigned short* dwb = (unsigned short*)(wbf_f + 1736704);  // dt_proj_w bf16
  // scan summaries overwrite the whole staging region after dt_proj:
  float* hend  = wbf_f;                  // [1048576] = B*NCHK*DI*NST
  float* aprod = wbf_f + 1048576;        // [1048576]

  // 1: convert in_proj_w -> bf16 (4096x1024)
  f2b_k<<<(4096 * 1024) / 1024, 256, 0, stream>>>(in_proj_w, wbf);
  // 2-3: LN0 (fp32), LN1 (bf16)
  ln_k<<<T_TOK, 256, 0, stream>>>(x_in, ln0_w, ln0_b, xws);
  ln_bf_k<<<T_TOK, 256, 0, stream>>>(xws, ln1_w, ln1_b, ubf);
  // 4: in_proj, single dispatch N=4096 -> xzb bf16 (512 blocks)
  {
    dim3 g((2 * DI) / 128, T_TOK / 128, 1);
    gemm_bf16<<<g, 256, 0, stream>>>(ubf, DM, wbf, DM, xzb, 2 * DI, DM, 1,
                                     nullptr, nullptr, nullptr, nullptr);
  }
  // 5: causal conv + silu (bf16 in) -> xc fp32 + xcb bf16
  conv_silu_k<<<(T_TOK * DI) / 256, 256, 0, stream>>>(xzb, conv_w, conv_b, xcws, xcb);
  // 6: x_proj / dt_proj weights -> bf16
  f2b_k<<<(XD * DI) / 1024, 256, 0, stream>>>(x_proj_w, wpb);
  f2b_k<<<(DI * DTR) / 1024, 256, 0, stream>>>(dt_proj_w, dwb);
  // 7: x_proj split-K MFMA + reduce -> xdbl fp32, dtb bf16
  {
    dim3 g(T_TOK / 64, SPLITK);
    xproj_k<<<g, 256, 0, stream>>>(xcb, wpb, part);
    xreduce_k<<<(T_TOK * XD) / 256, 256, 0, stream>>>(part, xdbl, dtb);
  }
  // 8: dt_proj + softplus (bf16 MFMA) -> delta fp32
  {
    dim3 g(DI / 128, T_TOK / 128, 1);
    gemm_bf16<<<g, 256, 0, stream>>>(dtb, DTR, dwb, DTR, dws, DI, DTR, 5,
                                     dt_proj_b, nullptr, nullptr, nullptr);
  }
  // 9-10: chunked scan, 4 states/thread (summaries alias dead staging region)
  {
    int nthreads = 2 * NCHK * DI * 4;  // 262144
    scan1_k<<<nthreads / 256, 256, 0, stream>>>(dws, xcws, xdbl, A_log,
                                                hend, aprod);
    scan2_k<<<nthreads / 256, 256, 0, stream>>>(dws, xcws, xdbl, xzb,
                                                A_log, D_skip, hend, aprod, ybf);
  }
  // 11: out_proj split-K x4 (512 blocks) + reduce(+res) -> xws
  f2b_k<<<(DM * DI) / 1024, 256, 0, stream>>>(out_proj_w, wbf);
  {
    dim3 g(DM / 128, T_TOK / 128, 4);
    gemm_bf16<<<g, 256, 0, stream>>>(ybf, DI, wbf, DI, nullptr, DM, DI / 4, 6,
                                     nullptr, nullptr, xcws, dws);
    reduce4_k<<<(T_TOK * DM) / 256, 256, 0, stream>>>(xcws, dws, xws, nullptr, xws);
  }
  // 12: LN2 -> bf16
  ln_bf_k<<<T_TOK, 256, 0, stream>>>(xws, ln2_w, ln2_b, ubf);
  // 13: ffn1 + bias + gelu -> hbf bf16 (512 blocks)
  f2b_k<<<(FFN * DM) / 1024, 256, 0, stream>>>(ffn_w1, wbf);
  {
    dim3 g(FFN / 128, T_TOK / 128, 1);
    gemm_bf16<<<g, 256, 0, stream>>>(ubf, DM, wbf, DM, hbf, FFN, DM, 2,
                                     ffn_b1, nullptr, nullptr, nullptr);
  }
  // 14: ffn2 split-K x4 (512 blocks) + reduce(+bias+res) -> d_out
  f2b_k<<<(DM * FFN) / 1024, 256, 0, stream>>>(ffn_w2, wbf);
  {
    dim3 g(DM / 128, T_TOK / 128, 4);
    gemm_bf16<<<g, 256, 0, stream>>>(hbf, FFN, wbf, FFN, nullptr, DM, FFN / 4, 6,
                                     nullptr, nullptr, dws, xcws);
    reduce4_k<<<(T_TOK * DM) / 256, 256, 0, stream>>>(dws, xcws, out, ffn_b2, xws);
  }
}